// Round 11
// baseline (176.432 us; speedup 1.0000x reference)
//
#include <hip/hip_runtime.h>
#include <hip/hip_bf16.h>

typedef __attribute__((ext_vector_type(4))) float f4;
typedef __attribute__((ext_vector_type(4))) int i4;
typedef __attribute__((ext_vector_type(8))) short s8;

#define MFMA16(a,b,c) __builtin_amdgcn_mfma_f32_16x16x32_bf16((a),(b),(c),0,0,0)

static __device__ __forceinline__ unsigned short f2bf(float x){
  return __builtin_bit_cast(unsigned short, __float2bfloat16(x));
}
// B-fragment-linear index for mfma_f32_16x16x32_bf16:
// lane l holds B[k = kt*32 + (l>>4)*8 + j][col = ct*16 + (l&15)], j=0..7
__device__ __forceinline__ int fidx(int kk, int c, int nct){
  return ((((kk >> 5) * nct + (c >> 4)) << 6) + (((kk >> 3) & 3) * 16 + (c & 15))) * 8 + (kk & 7);
}

// ---------------- prep kernels ----------------
__global__ void prep1(const float* __restrict__ Ws, const float* __restrict__ Wa1,
                      const float* __restrict__ Wo,
                      unsigned short* __restrict__ Ws2f, unsigned short* __restrict__ Wof,
                      unsigned short* __restrict__ WsWa1f){
  __shared__ float wrow[256];
  int i = blockIdx.x, t = threadIdx.x;
  wrow[t] = Ws[i*256 + t];
  __syncthreads();
  float a1 = 0.f;
  for (int t2 = 0; t2 < 256; ++t2) a1 += wrow[t2] * Ws[t2*256 + t];   // Ws2 = Ws@Ws
  Ws2f[fidx(i, t, 16)] = f2bf(a1);
  Wof[fidx(i, t, 16)]  = f2bf(Wo[i*256 + t]);
  if (t < 32){
    float a2 = 0.f;
    for (int t2 = 0; t2 < 256; ++t2) a2 += wrow[t2] * Wa1[t2*32 + t]; // WsWa1 = Ws@Wa1
    WsWa1f[fidx(i, t, 2)] = f2bf(a2);
  }
}

// 64 blocks x 256 threads (parallelized)
__global__ void prep2(const float* __restrict__ Wp2, const float* __restrict__ Wa2,
                      const float* __restrict__ Wa1, const float* __restrict__ bp2,
                      const float* __restrict__ ba1,
                      unsigned short* __restrict__ Wp2f, unsigned short* __restrict__ Wa2f,
                      unsigned short* __restrict__ Wp2Wa1f, float* __restrict__ bh){
  int gid = blockIdx.x * 256 + threadIdx.x;   // 0..16383
  if (gid < 8192){
    int kk = gid >> 8, c = gid & 255;
    Wp2f[fidx(kk, c, 16)] = f2bf(Wp2[gid]);
  } else {
    int g = gid - 8192; int kk = g >> 8, c = g & 255;
    Wa2f[fidx(kk, c, 16)] = f2bf(Wa2[g]);
  }
  if (gid < 1024){                     // Wp2Wa1 = Wp2@Wa1 [32][32]
    int h1 = gid >> 5, h2 = gid & 31;
    float a = 0.f;
    for (int c = 0; c < 256; ++c) a += Wp2[h1*256 + c] * Wa1[c*32 + h2];
    Wp2Wa1f[fidx(h1, h2, 2)] = f2bf(a);
  }
  if (gid < 32){                       // bh = bp2@Wa1 + ba1
    float a = ba1[gid];
    for (int c = 0; c < 256; ++c) a += bp2[c] * Wa1[c*32 + gid];
    bh[gid] = a;
  }
}

// ---------------- main kernel: phases B..E, x -> global bf16 ----------------
// Block = 4 n-rows. Phase B row-split (wave w <-> n w), phase E column-split
// (wave w <-> cols [64w,64w+64)) with ci-QUAD: ONE pass over kA feeds all 4
// ct columns (kA ds_reads 128->32 per wave vs R7). 16 NAMED f4 accumulators
// (R9/R10 lesson: named scalars only -- arrays/lambda-pointers spill).
__global__ __launch_bounds__(256, 4) void attn_x(
  const float* __restrict__ q, const float* __restrict__ k,
  const float* __restrict__ pos, const int* __restrict__ mask,
  const float* __restrict__ Wp1, const float* __restrict__ bp1,
  const float* __restrict__ bp2, const float* __restrict__ bh,
  const unsigned short* __restrict__ Ws2f, const unsigned short* __restrict__ WsWa1f,
  const unsigned short* __restrict__ Wp2f, const unsigned short* __restrict__ Wa2f,
  const unsigned short* __restrict__ Wp2Wa1f,
  unsigned short* __restrict__ xbuf)
{
  __shared__ unsigned short kA[16384];  // 32 KB: [n][kt][lane][8] bf16 A-frags of k
  __shared__ unsigned short phL[2048];  // 4 KB:  [n][lane][8] pos-hidden A-frags
  __shared__ unsigned short hL[2048];   // 4 KB:  [n][lane][8] attn-hidden A-frags

  const int t = threadIdx.x;
  const int lane = t & 63;
  const int w = t >> 6;
  const int lg = lane >> 4;
  const int lr = lane & 15;
  const int bn0 = blockIdx.x * 4;
  const int n0 = bn0 + w;
  const f4 z4 = {0.f, 0.f, 0.f, 0.f};

  // ---- Phase B: per-kt {k,q loads, convert, kA write, kh MFMAs}
  const float* krow = k + (size_t)n0 * 4096 + (size_t)lr * 256;
  const float* qrow = q + (size_t)n0 * 256;
  const unsigned short* wa1b = WsWa1f + (size_t)lane * 8;
  f4 khac[2] = {z4, z4};
  #pragma unroll
  for (int kt = 0; kt < 8; ++kt){
    int c0 = kt * 32 + lg * 8;
    f4 ka = *(const f4*)(krow + c0);
    f4 kb = *(const f4*)(krow + c0 + 4);
    f4 qa = *(const f4*)(qrow + c0);
    f4 qb = *(const f4*)(qrow + c0 + 4);
    s8 kf, mf;
    #pragma unroll
    for (int j = 0; j < 4; ++j){
      kf[j]     = (short)f2bf(ka[j]);
      kf[4 + j] = (short)f2bf(kb[j]);
      mf[j]     = (short)f2bf(ka[j] - qa[j]);
      mf[4 + j] = (short)f2bf(kb[j] - qb[j]);
    }
    *(s8*)(kA + ((w * 8 + kt) * 64 + lane) * 8) = kf;
    khac[0] = MFMA16(mf, *(const s8*)(wa1b + (size_t)(kt * 2 + 0) * 512), khac[0]);
    khac[1] = MFMA16(mf, *(const s8*)(wa1b + (size_t)(kt * 2 + 1) * 512), khac[1]);
  }

  // pos-MLP per-lane directly in A-frag layout
  s8 phfrag;
  {
    f4 pv = *(const f4*)(pos + (size_t)n0 * 64 + (size_t)lr * 4);
    f4 h0 = *(const f4*)(bp1 + lg * 8);
    f4 h1 = *(const f4*)(bp1 + lg * 8 + 4);
    #pragma unroll
    for (int p = 0; p < 4; ++p){
      f4 w0 = *(const f4*)(Wp1 + p * 32 + lg * 8);
      f4 w1 = *(const f4*)(Wp1 + p * 32 + lg * 8 + 4);
      #pragma unroll
      for (int j = 0; j < 4; ++j){ h0[j] += pv[p] * w0[j]; h1[j] += pv[p] * w1[j]; }
    }
    #pragma unroll
    for (int j = 0; j < 4; ++j){
      phfrag[j]     = (short)f2bf(fmaxf(h0[j], 0.f));
      phfrag[4 + j] = (short)f2bf(fmaxf(h1[j], 0.f));
    }
  }
  *(s8*)(phL + (w * 64 + lane) * 8) = phfrag;

  // khac += ph@Wp2Wa1
  {
    const unsigned short* wpwb = Wp2Wa1f + (size_t)lane * 8;
    khac[0] = MFMA16(phfrag, *(const s8*)(wpwb), khac[0]);
    khac[1] = MFMA16(phfrag, *(const s8*)(wpwb + 512), khac[1]);
  }

  // h = relu(khac + bh) scattered into hL A-frag slots
  #pragma unroll
  for (int ct2 = 0; ct2 < 2; ++ct2){
    float bhc = bh[ct2 * 16 + lr];
    #pragma unroll
    for (int r = 0; r < 4; ++r){
      int m = lg * 4 + r, col = ct2 * 16 + lr;
      hL[w * 512 + ((col >> 3) * 16 + m) * 8 + (col & 7)] = f2bf(fmaxf(khac[ct2][r] + bhc, 0.f));
    }
  }
  __syncthreads();

  // ---- Phase E: ci-QUAD, named accumulators, macro epilogue.
  const unsigned short* ws2b = Ws2f + (size_t)lane * 8;
  const unsigned short* wp2b = Wp2f + (size_t)lane * 8;
  const unsigned short* wa2b = Wa2f + (size_t)lane * 8;

#define EPI_N(VN, N, CT, BP, BA, BP2C) { \
    s8 pfr = *(const s8*)(phL + ((N) * 64 + lane) * 8); \
    s8 hfr = *(const s8*)(hL + ((N) * 64 + lane) * 8); \
    f4 pf = MFMA16(pfr, (BP), z4); \
    f4 aa = MFMA16(hfr, (BA), z4); \
    i4 mv = *(const i4*)(mask + (size_t)(bn0 + (N)) * 16 + lg * 4); \
    float lg0 = mv[0] ? aa[0] : -1e9f; \
    float lg1 = mv[1] ? aa[1] : -1e9f; \
    float lg2 = mv[2] ? aa[2] : -1e9f; \
    float lg3 = mv[3] ? aa[3] : -1e9f; \
    float mx = fmaxf(fmaxf(lg0, lg1), fmaxf(lg2, lg3)); \
    mx = fmaxf(mx, __shfl_xor(mx, 16)); \
    mx = fmaxf(mx, __shfl_xor(mx, 32)); \
    float p0 = __expf(lg0 - mx), p1 = __expf(lg1 - mx); \
    float p2 = __expf(lg2 - mx), p3 = __expf(lg3 - mx); \
    float den = p0 + p1 + p2 + p3; \
    float num = p0 * ((VN)[0] + pf[0] + (BP2C)) \
              + p1 * ((VN)[1] + pf[1] + (BP2C)) \
              + p2 * ((VN)[2] + pf[2] + (BP2C)) \
              + p3 * ((VN)[3] + pf[3] + (BP2C)); \
    den += __shfl_xor(den, 16); den += __shfl_xor(den, 32); \
    num += __shfl_xor(num, 16); num += __shfl_xor(num, 32); \
    if (lane < 16) \
      xbuf[(size_t)(bn0 + (N)) * 256 + (CT) * 16 + lr] = f2bf(__fdividef(num, den)); \
  }

#define EPILOGUE(V0, V1, V2, V3, CT) { \
    s8 bp = *(const s8*)(wp2b + (size_t)(CT) * 512); \
    s8 ba = *(const s8*)(wa2b + (size_t)(CT) * 512); \
    float bp2c = bp2[(CT) * 16 + lr]; \
    EPI_N(V0, 0, CT, bp, ba, bp2c); \
    EPI_N(V1, 1, CT, bp, ba, bp2c); \
    EPI_N(V2, 2, CT, bp, ba, bp2c); \
    EPI_N(V3, 3, CT, bp, ba, bp2c); \
  }

  {
    const int ct0 = w * 4;
    // vCN: C = ct offset 0..3, N = n 0..3 (16 named f4 accumulators = 64 VGPR)
    f4 v00 = z4, v01 = z4, v02 = z4, v03 = z4;
    f4 v10 = z4, v11 = z4, v12 = z4, v13 = z4;
    f4 v20 = z4, v21 = z4, v22 = z4, v23 = z4;
    f4 v30 = z4, v31 = z4, v32 = z4, v33 = z4;
    #pragma unroll
    for (int kt = 0; kt < 8; ++kt){
      s8 b0 = *(const s8*)(ws2b + (size_t)(kt * 16 + ct0 + 0) * 512);
      s8 b1 = *(const s8*)(ws2b + (size_t)(kt * 16 + ct0 + 1) * 512);
      s8 b2 = *(const s8*)(ws2b + (size_t)(kt * 16 + ct0 + 2) * 512);
      s8 b3 = *(const s8*)(ws2b + (size_t)(kt * 16 + ct0 + 3) * 512);
      s8 af0 = *(const s8*)(kA + ((0 * 8 + kt) * 64 + lane) * 8);
      s8 af1 = *(const s8*)(kA + ((1 * 8 + kt) * 64 + lane) * 8);
      s8 af2 = *(const s8*)(kA + ((2 * 8 + kt) * 64 + lane) * 8);
      s8 af3 = *(const s8*)(kA + ((3 * 8 + kt) * 64 + lane) * 8);
      v00 = MFMA16(af0, b0, v00); v01 = MFMA16(af1, b0, v01);
      v02 = MFMA16(af2, b0, v02); v03 = MFMA16(af3, b0, v03);
      v10 = MFMA16(af0, b1, v10); v11 = MFMA16(af1, b1, v11);
      v12 = MFMA16(af2, b1, v12); v13 = MFMA16(af3, b1, v13);
      v20 = MFMA16(af0, b2, v20); v21 = MFMA16(af1, b2, v21);
      v22 = MFMA16(af2, b2, v22); v23 = MFMA16(af3, b2, v23);
      v30 = MFMA16(af0, b3, v30); v31 = MFMA16(af1, b3, v31);
      v32 = MFMA16(af2, b3, v32); v33 = MFMA16(af3, b3, v33);
    }
    EPILOGUE(v00, v01, v02, v03, ct0 + 0);
    EPILOGUE(v10, v11, v12, v13, ct0 + 1);
    EPILOGUE(v20, v21, v22, v23, ct0 + 2);
    EPILOGUE(v30, v31, v32, v33, ct0 + 3);
  }
#undef EPILOGUE
#undef EPI_N
}

// ---------------- proj kernel: out = x @ Wo + bo ----------------
__global__ __launch_bounds__(128, 4) void proj(
  const unsigned short* __restrict__ xbuf, const unsigned short* __restrict__ Wof,
  const float* __restrict__ bo, float* __restrict__ out)
{
  const int t = threadIdx.x;
  const int lane = t & 63;
  const int w = t >> 6;
  const int lg = lane >> 4;
  const int lr = lane & 15;
  const int n0 = blockIdx.x * 32 + w * 16;
  const f4 z4 = {0.f, 0.f, 0.f, 0.f};
  const unsigned short* xr = xbuf + (size_t)(n0 + lr) * 256;
  const unsigned short* wob = Wof + (size_t)lane * 8;
  #pragma unroll
  for (int p = 0; p < 4; ++p){
    f4 oac[4] = {z4, z4, z4, z4};
    #pragma unroll
    for (int kt = 0; kt < 8; ++kt){
      s8 xf = *(const s8*)(xr + kt * 32 + lg * 8);
      #pragma unroll
      for (int ci = 0; ci < 4; ++ci)
        oac[ci] = MFMA16(xf, *(const s8*)(wob + (size_t)(kt * 16 + p * 4 + ci) * 512), oac[ci]);
    }
    #pragma unroll
    for (int ci = 0; ci < 4; ++ci){
      int c = (p * 4 + ci) * 16 + lr;
      float bov = bo[c];
      #pragma unroll
      for (int r = 0; r < 4; ++r)
        out[(size_t)(n0 + lg * 4 + r) * 256 + c] = oac[ci][r] + bov;
    }
  }
}

// ---------------- fallback monolithic kernel (R4, proven) ----------------
__global__ __launch_bounds__(256, 4) void attn_mono(
  const float* __restrict__ q, const float* __restrict__ k,
  const float* __restrict__ pos, const int* __restrict__ mask,
  const float* __restrict__ Wp1, const float* __restrict__ bp1,
  const float* __restrict__ bp2, const float* __restrict__ bo,
  const float* __restrict__ bh,
  const unsigned short* __restrict__ Ws2f, const unsigned short* __restrict__ WsWa1f,
  const unsigned short* __restrict__ Wp2f, const unsigned short* __restrict__ Wa2f,
  const unsigned short* __restrict__ Wp2Wa1f, const unsigned short* __restrict__ Wof,
  float* __restrict__ out)
{
  __shared__ unsigned short kA[16384];
  __shared__ unsigned short phL[2048];
  __shared__ unsigned short hL[2048];
  __shared__ unsigned short xT[4096];

  const int t = threadIdx.x;
  const int lane = t & 63;
  const int w = t >> 6;
  const int lg = lane >> 4;
  const int lr = lane & 15;
  const int bn0 = blockIdx.x * 4;
  const int n0 = bn0 + w;
  const f4 z4 = {0.f, 0.f, 0.f, 0.f};

  const float* krow = k + (size_t)n0 * 4096 + (size_t)lr * 256;
  const float* qrow = q + (size_t)n0 * 256;
  const unsigned short* wa1b = WsWa1f + (size_t)lane * 8;
  f4 khac[2] = {z4, z4};
  #pragma unroll
  for (int kt = 0; kt < 8; ++kt){
    int c0 = kt * 32 + lg * 8;
    f4 ka = *(const f4*)(krow + c0);
    f4 kb = *(const f4*)(krow + c0 + 4);
    f4 qa = *(const f4*)(qrow + c0);
    f4 qb = *(const f4*)(qrow + c0 + 4);
    s8 kf, mf;
    #pragma unroll
    for (int j = 0; j < 4; ++j){
      kf[j]     = (short)f2bf(ka[j]);
      kf[4 + j] = (short)f2bf(kb[j]);
      mf[j]     = (short)f2bf(ka[j] - qa[j]);
      mf[4 + j] = (short)f2bf(kb[j] - qb[j]);
    }
    *(s8*)(kA + ((w * 8 + kt) * 64 + lane) * 8) = kf;
    khac[0] = MFMA16(mf, *(const s8*)(wa1b + (size_t)(kt * 2 + 0) * 512), khac[0]);
    khac[1] = MFMA16(mf, *(const s8*)(wa1b + (size_t)(kt * 2 + 1) * 512), khac[1]);
  }
  s8 phfrag;
  {
    f4 pv = *(const f4*)(pos + (size_t)n0 * 64 + (size_t)lr * 4);
    f4 h0 = *(const f4*)(bp1 + lg * 8);
    f4 h1 = *(const f4*)(bp1 + lg * 8 + 4);
    #pragma unroll
    for (int p = 0; p < 4; ++p){
      f4 w0 = *(const f4*)(Wp1 + p * 32 + lg * 8);
      f4 w1 = *(const f4*)(Wp1 + p * 32 + lg * 8 + 4);
      #pragma unroll
      for (int j = 0; j < 4; ++j){ h0[j] += pv[p] * w0[j]; h1[j] += pv[p] * w1[j]; }
    }
    #pragma unroll
    for (int j = 0; j < 4; ++j){
      phfrag[j]     = (short)f2bf(fmaxf(h0[j], 0.f));
      phfrag[4 + j] = (short)f2bf(fmaxf(h1[j], 0.f));
    }
  }
  *(s8*)(phL + (w * 64 + lane) * 8) = phfrag;
  {
    const unsigned short* wpwb = Wp2Wa1f + (size_t)lane * 8;
    khac[0] = MFMA16(phfrag, *(const s8*)(wpwb), khac[0]);
    khac[1] = MFMA16(phfrag, *(const s8*)(wpwb + 512), khac[1]);
  }
  #pragma unroll
  for (int ct2 = 0; ct2 < 2; ++ct2){
    float bhc = bh[ct2 * 16 + lr];
    #pragma unroll
    for (int r = 0; r < 4; ++r){
      int m = lg * 4 + r, col = ct2 * 16 + lr;
      hL[w * 512 + ((col >> 3) * 16 + m) * 8 + (col & 7)] = f2bf(fmaxf(khac[ct2][r] + bhc, 0.f));
    }
  }
  __syncthreads();

  const unsigned short* ws2b = Ws2f + (size_t)lane * 8;
  const unsigned short* wp2b = Wp2f + (size_t)lane * 8;
  const unsigned short* wa2b = Wa2f + (size_t)lane * 8;
  #pragma unroll
  for (int ci = 0; ci < 4; ++ci){
    int ct = w * 4 + ci;
    f4 vacc[4] = {z4, z4, z4, z4};
    #pragma unroll
    for (int kt = 0; kt < 8; ++kt){
      s8 bw = *(const s8*)(ws2b + (size_t)(kt * 16 + ct) * 512);
      #pragma unroll
      for (int n = 0; n < 4; ++n){
        s8 af = *(const s8*)(kA + ((n * 8 + kt) * 64 + lane) * 8);
        vacc[n] = MFMA16(af, bw, vacc[n]);
      }
    }
    s8 bp = *(const s8*)(wp2b + (size_t)ct * 512);
    s8 ba = *(const s8*)(wa2b + (size_t)ct * 512);
    f4 pf[4], aa[4];
    #pragma unroll
    for (int n = 0; n < 4; ++n){
      s8 pfr = *(const s8*)(phL + (n * 64 + lane) * 8);
      s8 hfr = *(const s8*)(hL + (n * 64 + lane) * 8);
      pf[n] = MFMA16(pfr, bp, z4);
      aa[n] = MFMA16(hfr, ba, z4);
    }
    float bp2c = bp2[ct * 16 + lr];
    #pragma unroll
    for (int n = 0; n < 4; ++n){
      i4 mv = *(const i4*)(mask + (size_t)(bn0 + n) * 16 + lg * 4);
      float lg0 = mv[0] ? aa[n][0] : -1e9f;
      float lg1 = mv[1] ? aa[n][1] : -1e9f;
      float lg2 = mv[2] ? aa[n][2] : -1e9f;
      float lg3 = mv[3] ? aa[n][3] : -1e9f;
      float mx = fmaxf(fmaxf(lg0, lg1), fmaxf(lg2, lg3));
      mx = fmaxf(mx, __shfl_xor(mx, 16));
      mx = fmaxf(mx, __shfl_xor(mx, 32));
      float p0 = __expf(lg0 - mx), p1 = __expf(lg1 - mx);
      float p2 = __expf(lg2 - mx), p3 = __expf(lg3 - mx);
      float den = p0 + p1 + p2 + p3;
      float num = p0 * (vacc[n][0] + pf[n][0] + bp2c)
                + p1 * (vacc[n][1] + pf[n][1] + bp2c)
                + p2 * (vacc[n][2] + pf[n][2] + bp2c)
                + p3 * (vacc[n][3] + pf[n][3] + bp2c);
      den += __shfl_xor(den, 16); den += __shfl_xor(den, 32);
      num += __shfl_xor(num, 16); num += __shfl_xor(num, 32);
      if (lane < 16){
        int c = ct * 16 + lr;
        xT[((c >> 5) * 64 + ((c >> 3) & 3) * 16 + n) * 8 + (c & 7)] = f2bf(__fdividef(num, den));
      }
    }
  }
  __syncthreads();

  f4 oac[4] = {z4, z4, z4, z4};
  const unsigned short* wob = Wof + (size_t)lane * 8;
  #pragma unroll
  for (int kt = 0; kt < 8; ++kt){
    s8 xf = *(const s8*)(xT + (kt * 64 + lane) * 8);
    #pragma unroll
    for (int ci = 0; ci < 4; ++ci)
      oac[ci] = MFMA16(xf, *(const s8*)(wob + (size_t)(kt * 16 + w * 4 + ci) * 512), oac[ci]);
  }
  if (lane < 16){
    #pragma unroll
    for (int ci = 0; ci < 4; ++ci){
      int c = (w * 4 + ci) * 16 + lr;
      float bov = bo[c];
      #pragma unroll
      for (int r = 0; r < 4; ++r)
        out[(size_t)(bn0 + r) * 256 + c] = oac[ci][r] + bov;
    }
  }
}

extern "C" void kernel_launch(void* const* d_in, const int* in_sizes, int n_in,
                              void* d_out, int out_size, void* d_ws, size_t ws_size,
                              hipStream_t stream) {
  (void)in_sizes; (void)n_in; (void)out_size;
  const float* q   = (const float*)d_in[0];
  const float* k   = (const float*)d_in[1];
  const float* pos = (const float*)d_in[2];
  const int*   msk = (const int*)d_in[3];
  const float* Ws  = (const float*)d_in[4];
  const float* Wp1 = (const float*)d_in[5];
  const float* bp1 = (const float*)d_in[6];
  const float* Wp2 = (const float*)d_in[7];
  const float* bp2 = (const float*)d_in[8];
  const float* Wa1 = (const float*)d_in[9];
  const float* ba1 = (const float*)d_in[10];
  const float* Wa2 = (const float*)d_in[11];
  // d_in[12] = ba2: constant along softmax axis -> mathematically a no-op
  const float* Wo  = (const float*)d_in[13];
  const float* bo  = (const float*)d_in[14];

  if (ws_size < 313472) return;
  char* ws = (char*)d_ws;
  unsigned short* Ws2f    = (unsigned short*)(ws + 0);       // 131072 B
  unsigned short* Wof     = (unsigned short*)(ws + 131072);  // 131072 B
  unsigned short* WsWa1f  = (unsigned short*)(ws + 262144);  // 16384 B
  unsigned short* Wp2f    = (unsigned short*)(ws + 278528);  // 16384 B
  unsigned short* Wa2f    = (unsigned short*)(ws + 294912);  // 16384 B
  unsigned short* Wp2Wa1f = (unsigned short*)(ws + 311296);  // 2048 B
  float*          bh      = (float*)(ws + 313344);           // 128 B
  unsigned short* xbuf    = (unsigned short*)(ws + 313472);  // 8388608 B

  prep1<<<dim3(256), dim3(256), 0, stream>>>(Ws, Wa1, Wo, Ws2f, Wof, WsWa1f);
  prep2<<<dim3(64), dim3(256), 0, stream>>>(Wp2, Wa2, Wa1, bp2, ba1, Wp2f, Wa2f, Wp2Wa1f, bh);

  if (ws_size >= 313472 + 8388608) {
    attn_x<<<dim3(4096), dim3(256), 0, stream>>>(q, k, pos, msk, Wp1, bp1, bp2, bh,
                                                 Ws2f, WsWa1f, Wp2f, Wa2f, Wp2Wa1f, xbuf);
    proj<<<dim3(512), dim3(128), 0, stream>>>(xbuf, Wof, bo, (float*)d_out);
  } else {
    attn_mono<<<dim3(4096), dim3(256), 0, stream>>>(q, k, pos, msk, Wp1, bp1, bp2, bo, bh,
                                                    Ws2f, WsWa1f, Wp2f, Wa2f, Wp2Wa1f, Wof,
                                                    (float*)d_out);
  }
}

// Round 12
// 168.052 us; speedup vs baseline: 1.0499x; 1.0499x over previous
//
#include <hip/hip_runtime.h>
#include <hip/hip_bf16.h>

typedef __attribute__((ext_vector_type(4))) float f4;
typedef __attribute__((ext_vector_type(4))) int i4;
typedef __attribute__((ext_vector_type(8))) short s8;

#define MFMA16(a,b,c) __builtin_amdgcn_mfma_f32_16x16x32_bf16((a),(b),(c),0,0,0)

static __device__ __forceinline__ unsigned short f2bf(float x){
  return __builtin_bit_cast(unsigned short, __float2bfloat16(x));
}
// B-fragment-linear index for mfma_f32_16x16x32_bf16:
// lane l holds B[k = kt*32 + (l>>4)*8 + j][col = ct*16 + (l&15)], j=0..7
__device__ __forceinline__ int fidx(int kk, int c, int nct){
  return ((((kk >> 5) * nct + (c >> 4)) << 6) + (((kk >> 3) & 3) * 16 + (c & 15))) * 8 + (kk & 7);
}

// ---------------- prep kernels ----------------
__global__ void prep1(const float* __restrict__ Ws, const float* __restrict__ Wa1,
                      const float* __restrict__ Wo,
                      unsigned short* __restrict__ Ws2f, unsigned short* __restrict__ Wof,
                      unsigned short* __restrict__ WsWa1f){
  __shared__ float wrow[256];
  int i = blockIdx.x, t = threadIdx.x;
  wrow[t] = Ws[i*256 + t];
  __syncthreads();
  float a1 = 0.f;
  for (int t2 = 0; t2 < 256; ++t2) a1 += wrow[t2] * Ws[t2*256 + t];   // Ws2 = Ws@Ws
  Ws2f[fidx(i, t, 16)] = f2bf(a1);
  Wof[fidx(i, t, 16)]  = f2bf(Wo[i*256 + t]);
  if (t < 32){
    float a2 = 0.f;
    for (int t2 = 0; t2 < 256; ++t2) a2 += wrow[t2] * Wa1[t2*32 + t]; // WsWa1 = Ws@Wa1
    WsWa1f[fidx(i, t, 2)] = f2bf(a2);
  }
}

// 64 blocks x 256 threads (parallelized)
__global__ void prep2(const float* __restrict__ Wp2, const float* __restrict__ Wa2,
                      const float* __restrict__ Wa1, const float* __restrict__ bp2,
                      const float* __restrict__ ba1,
                      unsigned short* __restrict__ Wp2f, unsigned short* __restrict__ Wa2f,
                      unsigned short* __restrict__ Wp2Wa1f, float* __restrict__ bh){
  int gid = blockIdx.x * 256 + threadIdx.x;   // 0..16383
  if (gid < 8192){
    int kk = gid >> 8, c = gid & 255;
    Wp2f[fidx(kk, c, 16)] = f2bf(Wp2[gid]);
  } else {
    int g = gid - 8192; int kk = g >> 8, c = g & 255;
    Wa2f[fidx(kk, c, 16)] = f2bf(Wa2[g]);
  }
  if (gid < 1024){                     // Wp2Wa1 = Wp2@Wa1 [32][32]
    int h1 = gid >> 5, h2 = gid & 31;
    float a = 0.f;
    for (int c = 0; c < 256; ++c) a += Wp2[h1*256 + c] * Wa1[c*32 + h2];
    Wp2Wa1f[fidx(h1, h2, 2)] = f2bf(a);
  }
  if (gid < 32){                       // bh = bp2@Wa1 + ba1
    float a = ba1[gid];
    for (int c = 0; c < 256; ++c) a += bp2[c] * Wa1[c*32 + gid];
    bh[gid] = a;
  }
}

// ---------------- main kernel: phases B..E, x -> global bf16 ----------------
// Block = 4 n-rows. Phase B row-split (wave w <-> n w), phase E column-split
// (wave w <-> cols [64w,64w+64)) with ci-PAIRING via NAMED accumulators.
// amdgpu_waves_per_eu(4,4): LDS caps us at 4 blocks/CU (= 4 waves/EU) anyway;
// clamping the allocator's occupancy target to 4 grants the full 128-VGPR
// budget and stops the 64-VGPR-pin + scratch-spill seen in R3..R11.
__global__ __attribute__((amdgpu_flat_work_group_size(256,256), amdgpu_waves_per_eu(4,4)))
void attn_x(
  const float* __restrict__ q, const float* __restrict__ k,
  const float* __restrict__ pos, const int* __restrict__ mask,
  const float* __restrict__ Wp1, const float* __restrict__ bp1,
  const float* __restrict__ bp2, const float* __restrict__ bh,
  const unsigned short* __restrict__ Ws2f, const unsigned short* __restrict__ WsWa1f,
  const unsigned short* __restrict__ Wp2f, const unsigned short* __restrict__ Wa2f,
  const unsigned short* __restrict__ Wp2Wa1f,
  unsigned short* __restrict__ xbuf)
{
  __shared__ unsigned short kA[16384];  // 32 KB: [n][kt][lane][8] bf16 A-frags of k
  __shared__ unsigned short phL[2048];  // 4 KB:  [n][lane][8] pos-hidden A-frags
  __shared__ unsigned short hL[2048];   // 4 KB:  [n][lane][8] attn-hidden A-frags

  const int t = threadIdx.x;
  const int lane = t & 63;
  const int w = t >> 6;
  const int lg = lane >> 4;
  const int lr = lane & 15;
  const int bn0 = blockIdx.x * 4;
  const int n0 = bn0 + w;
  const f4 z4 = {0.f, 0.f, 0.f, 0.f};

  // ---- Phase B: per-kt {k,q loads, convert, kA write, kh MFMAs}
  const float* krow = k + (size_t)n0 * 4096 + (size_t)lr * 256;
  const float* qrow = q + (size_t)n0 * 256;
  const unsigned short* wa1b = WsWa1f + (size_t)lane * 8;
  f4 khac[2] = {z4, z4};
  #pragma unroll
  for (int kt = 0; kt < 8; ++kt){
    int c0 = kt * 32 + lg * 8;
    f4 ka = *(const f4*)(krow + c0);
    f4 kb = *(const f4*)(krow + c0 + 4);
    f4 qa = *(const f4*)(qrow + c0);
    f4 qb = *(const f4*)(qrow + c0 + 4);
    s8 kf, mf;
    #pragma unroll
    for (int j = 0; j < 4; ++j){
      kf[j]     = (short)f2bf(ka[j]);
      kf[4 + j] = (short)f2bf(kb[j]);
      mf[j]     = (short)f2bf(ka[j] - qa[j]);
      mf[4 + j] = (short)f2bf(kb[j] - qb[j]);
    }
    *(s8*)(kA + ((w * 8 + kt) * 64 + lane) * 8) = kf;
    khac[0] = MFMA16(mf, *(const s8*)(wa1b + (size_t)(kt * 2 + 0) * 512), khac[0]);
    khac[1] = MFMA16(mf, *(const s8*)(wa1b + (size_t)(kt * 2 + 1) * 512), khac[1]);
  }

  // pos-MLP per-lane directly in A-frag layout
  s8 phfrag;
  {
    f4 pv = *(const f4*)(pos + (size_t)n0 * 64 + (size_t)lr * 4);
    f4 h0 = *(const f4*)(bp1 + lg * 8);
    f4 h1 = *(const f4*)(bp1 + lg * 8 + 4);
    #pragma unroll
    for (int p = 0; p < 4; ++p){
      f4 w0 = *(const f4*)(Wp1 + p * 32 + lg * 8);
      f4 w1 = *(const f4*)(Wp1 + p * 32 + lg * 8 + 4);
      #pragma unroll
      for (int j = 0; j < 4; ++j){ h0[j] += pv[p] * w0[j]; h1[j] += pv[p] * w1[j]; }
    }
    #pragma unroll
    for (int j = 0; j < 4; ++j){
      phfrag[j]     = (short)f2bf(fmaxf(h0[j], 0.f));
      phfrag[4 + j] = (short)f2bf(fmaxf(h1[j], 0.f));
    }
  }
  *(s8*)(phL + (w * 64 + lane) * 8) = phfrag;

  // khac += ph@Wp2Wa1
  {
    const unsigned short* wpwb = Wp2Wa1f + (size_t)lane * 8;
    khac[0] = MFMA16(phfrag, *(const s8*)(wpwb), khac[0]);
    khac[1] = MFMA16(phfrag, *(const s8*)(wpwb + 512), khac[1]);
  }

  // h = relu(khac + bh) scattered into hL A-frag slots
  #pragma unroll
  for (int ct2 = 0; ct2 < 2; ++ct2){
    float bhc = bh[ct2 * 16 + lr];
    #pragma unroll
    for (int r = 0; r < 4; ++r){
      int m = lg * 4 + r, col = ct2 * 16 + lr;
      hL[w * 512 + ((col >> 3) * 16 + m) * 8 + (col & 7)] = f2bf(fmaxf(khac[ct2][r] + bhc, 0.f));
    }
  }
  __syncthreads();

  // ---- Phase E: column-split with ci-pairs, NAMED accumulators, macro epilogue.
  const unsigned short* ws2b = Ws2f + (size_t)lane * 8;
  const unsigned short* wp2b = Wp2f + (size_t)lane * 8;
  const unsigned short* wa2b = Wa2f + (size_t)lane * 8;

#define EPI_N(VN, N, CT, BP, BA, BP2C) { \
    s8 pfr = *(const s8*)(phL + ((N) * 64 + lane) * 8); \
    s8 hfr = *(const s8*)(hL + ((N) * 64 + lane) * 8); \
    f4 pf = MFMA16(pfr, (BP), z4); \
    f4 aa = MFMA16(hfr, (BA), z4); \
    i4 mv = *(const i4*)(mask + (size_t)(bn0 + (N)) * 16 + lg * 4); \
    float lg0 = mv[0] ? aa[0] : -1e9f; \
    float lg1 = mv[1] ? aa[1] : -1e9f; \
    float lg2 = mv[2] ? aa[2] : -1e9f; \
    float lg3 = mv[3] ? aa[3] : -1e9f; \
    float mx = fmaxf(fmaxf(lg0, lg1), fmaxf(lg2, lg3)); \
    mx = fmaxf(mx, __shfl_xor(mx, 16)); \
    mx = fmaxf(mx, __shfl_xor(mx, 32)); \
    float p0 = __expf(lg0 - mx), p1 = __expf(lg1 - mx); \
    float p2 = __expf(lg2 - mx), p3 = __expf(lg3 - mx); \
    float den = p0 + p1 + p2 + p3; \
    float num = p0 * ((VN)[0] + pf[0] + (BP2C)) \
              + p1 * ((VN)[1] + pf[1] + (BP2C)) \
              + p2 * ((VN)[2] + pf[2] + (BP2C)) \
              + p3 * ((VN)[3] + pf[3] + (BP2C)); \
    den += __shfl_xor(den, 16); den += __shfl_xor(den, 32); \
    num += __shfl_xor(num, 16); num += __shfl_xor(num, 32); \
    if (lane < 16) \
      xbuf[(size_t)(bn0 + (N)) * 256 + (CT) * 16 + lr] = f2bf(__fdividef(num, den)); \
  }

#define EPILOGUE(V0, V1, V2, V3, CT) { \
    s8 bp = *(const s8*)(wp2b + (size_t)(CT) * 512); \
    s8 ba = *(const s8*)(wa2b + (size_t)(CT) * 512); \
    float bp2c = bp2[(CT) * 16 + lr]; \
    EPI_N(V0, 0, CT, bp, ba, bp2c); \
    EPI_N(V1, 1, CT, bp, ba, bp2c); \
    EPI_N(V2, 2, CT, bp, ba, bp2c); \
    EPI_N(V3, 3, CT, bp, ba, bp2c); \
  }

  #pragma unroll
  for (int cp = 0; cp < 2; ++cp){
    const int ct0 = w * 4 + cp * 2;
    const int ct1 = ct0 + 1;
    f4 v00 = z4, v01 = z4, v02 = z4, v03 = z4;   // ct0, n=0..3
    f4 v10 = z4, v11 = z4, v12 = z4, v13 = z4;   // ct1, n=0..3
    #pragma unroll
    for (int kt = 0; kt < 8; ++kt){
      s8 b0 = *(const s8*)(ws2b + (size_t)(kt * 16 + ct0) * 512);
      s8 b1 = *(const s8*)(ws2b + (size_t)(kt * 16 + ct1) * 512);
      s8 af0 = *(const s8*)(kA + ((0 * 8 + kt) * 64 + lane) * 8);
      s8 af1 = *(const s8*)(kA + ((1 * 8 + kt) * 64 + lane) * 8);
      s8 af2 = *(const s8*)(kA + ((2 * 8 + kt) * 64 + lane) * 8);
      s8 af3 = *(const s8*)(kA + ((3 * 8 + kt) * 64 + lane) * 8);
      v00 = MFMA16(af0, b0, v00); v10 = MFMA16(af0, b1, v10);
      v01 = MFMA16(af1, b0, v01); v11 = MFMA16(af1, b1, v11);
      v02 = MFMA16(af2, b0, v02); v12 = MFMA16(af2, b1, v12);
      v03 = MFMA16(af3, b0, v03); v13 = MFMA16(af3, b1, v13);
    }
    EPILOGUE(v00, v01, v02, v03, ct0);
    EPILOGUE(v10, v11, v12, v13, ct1);
  }
#undef EPILOGUE
#undef EPI_N
}

// ---------------- proj kernel: out = x @ Wo + bo ----------------
__global__ __launch_bounds__(128, 4) void proj(
  const unsigned short* __restrict__ xbuf, const unsigned short* __restrict__ Wof,
  const float* __restrict__ bo, float* __restrict__ out)
{
  const int t = threadIdx.x;
  const int lane = t & 63;
  const int w = t >> 6;
  const int lg = lane >> 4;
  const int lr = lane & 15;
  const int n0 = blockIdx.x * 32 + w * 16;
  const f4 z4 = {0.f, 0.f, 0.f, 0.f};
  const unsigned short* xr = xbuf + (size_t)(n0 + lr) * 256;
  const unsigned short* wob = Wof + (size_t)lane * 8;
  #pragma unroll
  for (int p = 0; p < 4; ++p){
    f4 oac[4] = {z4, z4, z4, z4};
    #pragma unroll
    for (int kt = 0; kt < 8; ++kt){
      s8 xf = *(const s8*)(xr + kt * 32 + lg * 8);
      #pragma unroll
      for (int ci = 0; ci < 4; ++ci)
        oac[ci] = MFMA16(xf, *(const s8*)(wob + (size_t)(kt * 16 + p * 4 + ci) * 512), oac[ci]);
    }
    #pragma unroll
    for (int ci = 0; ci < 4; ++ci){
      int c = (p * 4 + ci) * 16 + lr;
      float bov = bo[c];
      #pragma unroll
      for (int r = 0; r < 4; ++r)
        out[(size_t)(n0 + lg * 4 + r) * 256 + c] = oac[ci][r] + bov;
    }
  }
}

// ---------------- fallback monolithic kernel (R4, proven) ----------------
__global__ __launch_bounds__(256, 4) void attn_mono(
  const float* __restrict__ q, const float* __restrict__ k,
  const float* __restrict__ pos, const int* __restrict__ mask,
  const float* __restrict__ Wp1, const float* __restrict__ bp1,
  const float* __restrict__ bp2, const float* __restrict__ bo,
  const float* __restrict__ bh,
  const unsigned short* __restrict__ Ws2f, const unsigned short* __restrict__ WsWa1f,
  const unsigned short* __restrict__ Wp2f, const unsigned short* __restrict__ Wa2f,
  const unsigned short* __restrict__ Wp2Wa1f, const unsigned short* __restrict__ Wof,
  float* __restrict__ out)
{
  __shared__ unsigned short kA[16384];
  __shared__ unsigned short phL[2048];
  __shared__ unsigned short hL[2048];
  __shared__ unsigned short xT[4096];

  const int t = threadIdx.x;
  const int lane = t & 63;
  const int w = t >> 6;
  const int lg = lane >> 4;
  const int lr = lane & 15;
  const int bn0 = blockIdx.x * 4;
  const int n0 = bn0 + w;
  const f4 z4 = {0.f, 0.f, 0.f, 0.f};

  const float* krow = k + (size_t)n0 * 4096 + (size_t)lr * 256;
  const float* qrow = q + (size_t)n0 * 256;
  const unsigned short* wa1b = WsWa1f + (size_t)lane * 8;
  f4 khac[2] = {z4, z4};
  #pragma unroll
  for (int kt = 0; kt < 8; ++kt){
    int c0 = kt * 32 + lg * 8;
    f4 ka = *(const f4*)(krow + c0);
    f4 kb = *(const f4*)(krow + c0 + 4);
    f4 qa = *(const f4*)(qrow + c0);
    f4 qb = *(const f4*)(qrow + c0 + 4);
    s8 kf, mf;
    #pragma unroll
    for (int j = 0; j < 4; ++j){
      kf[j]     = (short)f2bf(ka[j]);
      kf[4 + j] = (short)f2bf(kb[j]);
      mf[j]     = (short)f2bf(ka[j] - qa[j]);
      mf[4 + j] = (short)f2bf(kb[j] - qb[j]);
    }
    *(s8*)(kA + ((w * 8 + kt) * 64 + lane) * 8) = kf;
    khac[0] = MFMA16(mf, *(const s8*)(wa1b + (size_t)(kt * 2 + 0) * 512), khac[0]);
    khac[1] = MFMA16(mf, *(const s8*)(wa1b + (size_t)(kt * 2 + 1) * 512), khac[1]);
  }
  s8 phfrag;
  {
    f4 pv = *(const f4*)(pos + (size_t)n0 * 64 + (size_t)lr * 4);
    f4 h0 = *(const f4*)(bp1 + lg * 8);
    f4 h1 = *(const f4*)(bp1 + lg * 8 + 4);
    #pragma unroll
    for (int p = 0; p < 4; ++p){
      f4 w0 = *(const f4*)(Wp1 + p * 32 + lg * 8);
      f4 w1 = *(const f4*)(Wp1 + p * 32 + lg * 8 + 4);
      #pragma unroll
      for (int j = 0; j < 4; ++j){ h0[j] += pv[p] * w0[j]; h1[j] += pv[p] * w1[j]; }
    }
    #pragma unroll
    for (int j = 0; j < 4; ++j){
      phfrag[j]     = (short)f2bf(fmaxf(h0[j], 0.f));
      phfrag[4 + j] = (short)f2bf(fmaxf(h1[j], 0.f));
    }
  }
  *(s8*)(phL + (w * 64 + lane) * 8) = phfrag;
  {
    const unsigned short* wpwb = Wp2Wa1f + (size_t)lane * 8;
    khac[0] = MFMA16(phfrag, *(const s8*)(wpwb), khac[0]);
    khac[1] = MFMA16(phfrag, *(const s8*)(wpwb + 512), khac[1]);
  }
  #pragma unroll
  for (int ct2 = 0; ct2 < 2; ++ct2){
    float bhc = bh[ct2 * 16 + lr];
    #pragma unroll
    for (int r = 0; r < 4; ++r){
      int m = lg * 4 + r, col = ct2 * 16 + lr;
      hL[w * 512 + ((col >> 3) * 16 + m) * 8 + (col & 7)] = f2bf(fmaxf(khac[ct2][r] + bhc, 0.f));
    }
  }
  __syncthreads();

  const unsigned short* ws2b = Ws2f + (size_t)lane * 8;
  const unsigned short* wp2b = Wp2f + (size_t)lane * 8;
  const unsigned short* wa2b = Wa2f + (size_t)lane * 8;
  #pragma unroll
  for (int ci = 0; ci < 4; ++ci){
    int ct = w * 4 + ci;
    f4 vacc[4] = {z4, z4, z4, z4};
    #pragma unroll
    for (int kt = 0; kt < 8; ++kt){
      s8 bw = *(const s8*)(ws2b + (size_t)(kt * 16 + ct) * 512);
      #pragma unroll
      for (int n = 0; n < 4; ++n){
        s8 af = *(const s8*)(kA + ((n * 8 + kt) * 64 + lane) * 8);
        vacc[n] = MFMA16(af, bw, vacc[n]);
      }
    }
    s8 bp = *(const s8*)(wp2b + (size_t)ct * 512);
    s8 ba = *(const s8*)(wa2b + (size_t)ct * 512);
    f4 pf[4], aa[4];
    #pragma unroll
    for (int n = 0; n < 4; ++n){
      s8 pfr = *(const s8*)(phL + (n * 64 + lane) * 8);
      s8 hfr = *(const s8*)(hL + (n * 64 + lane) * 8);
      pf[n] = MFMA16(pfr, bp, z4);
      aa[n] = MFMA16(hfr, ba, z4);
    }
    float bp2c = bp2[ct * 16 + lr];
    #pragma unroll
    for (int n = 0; n < 4; ++n){
      i4 mv = *(const i4*)(mask + (size_t)(bn0 + n) * 16 + lg * 4);
      float lg0 = mv[0] ? aa[n][0] : -1e9f;
      float lg1 = mv[1] ? aa[n][1] : -1e9f;
      float lg2 = mv[2] ? aa[n][2] : -1e9f;
      float lg3 = mv[3] ? aa[n][3] : -1e9f;
      float mx = fmaxf(fmaxf(lg0, lg1), fmaxf(lg2, lg3));
      mx = fmaxf(mx, __shfl_xor(mx, 16));
      mx = fmaxf(mx, __shfl_xor(mx, 32));
      float p0 = __expf(lg0 - mx), p1 = __expf(lg1 - mx);
      float p2 = __expf(lg2 - mx), p3 = __expf(lg3 - mx);
      float den = p0 + p1 + p2 + p3;
      float num = p0 * (vacc[n][0] + pf[n][0] + bp2c)
                + p1 * (vacc[n][1] + pf[n][1] + bp2c)
                + p2 * (vacc[n][2] + pf[n][2] + bp2c)
                + p3 * (vacc[n][3] + pf[n][3] + bp2c);
      den += __shfl_xor(den, 16); den += __shfl_xor(den, 32);
      num += __shfl_xor(num, 16); num += __shfl_xor(num, 32);
      if (lane < 16){
        int c = ct * 16 + lr;
        xT[((c >> 5) * 64 + ((c >> 3) & 3) * 16 + n) * 8 + (c & 7)] = f2bf(__fdividef(num, den));
      }
    }
  }
  __syncthreads();

  f4 oac[4] = {z4, z4, z4, z4};
  const unsigned short* wob = Wof + (size_t)lane * 8;
  #pragma unroll
  for (int kt = 0; kt < 8; ++kt){
    s8 xf = *(const s8*)(xT + (kt * 64 + lane) * 8);
    #pragma unroll
    for (int ci = 0; ci < 4; ++ci)
      oac[ci] = MFMA16(xf, *(const s8*)(wob + (size_t)(kt * 16 + w * 4 + ci) * 512), oac[ci]);
  }
  if (lane < 16){
    #pragma unroll
    for (int ci = 0; ci < 4; ++ci){
      int c = (w * 4 + ci) * 16 + lr;
      float bov = bo[c];
      #pragma unroll
      for (int r = 0; r < 4; ++r)
        out[(size_t)(bn0 + r) * 256 + c] = oac[ci][r] + bov;
    }
  }
}

extern "C" void kernel_launch(void* const* d_in, const int* in_sizes, int n_in,
                              void* d_out, int out_size, void* d_ws, size_t ws_size,
                              hipStream_t stream) {
  (void)in_sizes; (void)n_in; (void)out_size;
  const float* q   = (const float*)d_in[0];
  const float* k   = (const float*)d_in[1];
  const float* pos = (const float*)d_in[2];
  const int*   msk = (const int*)d_in[3];
  const float* Ws  = (const float*)d_in[4];
  const float* Wp1 = (const float*)d_in[5];
  const float* bp1 = (const float*)d_in[6];
  const float* Wp2 = (const float*)d_in[7];
  const float* bp2 = (const float*)d_in[8];
  const float* Wa1 = (const float*)d_in[9];
  const float* ba1 = (const float*)d_in[10];
  const float* Wa2 = (const float*)d_in[11];
  // d_in[12] = ba2: constant along softmax axis -> mathematically a no-op
  const float* Wo  = (const float*)d_in[13];
  const float* bo  = (const float*)d_in[14];

  if (ws_size < 313472) return;
  char* ws = (char*)d_ws;
  unsigned short* Ws2f    = (unsigned short*)(ws + 0);       // 131072 B
  unsigned short* Wof     = (unsigned short*)(ws + 131072);  // 131072 B
  unsigned short* WsWa1f  = (unsigned short*)(ws + 262144);  // 16384 B
  unsigned short* Wp2f    = (unsigned short*)(ws + 278528);  // 16384 B
  unsigned short* Wa2f    = (unsigned short*)(ws + 294912);  // 16384 B
  unsigned short* Wp2Wa1f = (unsigned short*)(ws + 311296);  // 2048 B
  float*          bh      = (float*)(ws + 313344);           // 128 B
  unsigned short* xbuf    = (unsigned short*)(ws + 313472);  // 8388608 B

  prep1<<<dim3(256), dim3(256), 0, stream>>>(Ws, Wa1, Wo, Ws2f, Wof, WsWa1f);
  prep2<<<dim3(64), dim3(256), 0, stream>>>(Wp2, Wa2, Wa1, bp2, ba1, Wp2f, Wa2f, Wp2Wa1f, bh);

  if (ws_size >= 313472 + 8388608) {
    attn_x<<<dim3(4096), dim3(256), 0, stream>>>(q, k, pos, msk, Wp1, bp1, bp2, bh,
                                                 Ws2f, WsWa1f, Wp2f, Wa2f, Wp2Wa1f, xbuf);
    proj<<<dim3(512), dim3(128), 0, stream>>>(xbuf, Wof, bo, (float*)d_out);
  } else {
    attn_mono<<<dim3(4096), dim3(256), 0, stream>>>(q, k, pos, msk, Wp1, bp1, bp2, bo, bh,
                                                    Ws2f, WsWa1f, Wp2f, Wa2f, Wp2Wa1f, Wof,
                                                    (float*)d_out);
  }
}

// Round 13
// 157.361 us; speedup vs baseline: 1.1212x; 1.0679x over previous
//
#include <hip/hip_runtime.h>
#include <hip/hip_bf16.h>

typedef __attribute__((ext_vector_type(4))) float f4;
typedef __attribute__((ext_vector_type(4))) int i4;
typedef __attribute__((ext_vector_type(8))) short s8;
typedef __attribute__((ext_vector_type(4))) short s4;

#define MFMA16(a,b,c) __builtin_amdgcn_mfma_f32_16x16x32_bf16((a),(b),(c),0,0,0)

static __device__ __forceinline__ unsigned short f2bf(float x){
  return __builtin_bit_cast(unsigned short, __float2bfloat16(x));
}
// B-fragment-linear index for mfma_f32_16x16x32_bf16:
// lane l holds B[k = kt*32 + (l>>4)*8 + j][col = ct*16 + (l&15)], j=0..7
__device__ __forceinline__ int fidx(int kk, int c, int nct){
  return ((((kk >> 5) * nct + (c >> 4)) << 6) + (((kk >> 3) & 3) * 16 + (c & 15))) * 8 + (kk & 7);
}

// ---------------- prep kernels ----------------
__global__ void prep1(const float* __restrict__ Ws, const float* __restrict__ Wa1,
                      const float* __restrict__ Wo,
                      unsigned short* __restrict__ Ws2f, unsigned short* __restrict__ Wof,
                      unsigned short* __restrict__ WsWa1f){
  __shared__ float wrow[256];
  int i = blockIdx.x, t = threadIdx.x;
  wrow[t] = Ws[i*256 + t];
  __syncthreads();
  float a1 = 0.f;
  for (int t2 = 0; t2 < 256; ++t2) a1 += wrow[t2] * Ws[t2*256 + t];   // Ws2 = Ws@Ws
  Ws2f[fidx(i, t, 16)] = f2bf(a1);
  Wof[fidx(i, t, 16)]  = f2bf(Wo[i*256 + t]);
  if (t < 32){
    float a2 = 0.f;
    for (int t2 = 0; t2 < 256; ++t2) a2 += wrow[t2] * Wa1[t2*32 + t]; // WsWa1 = Ws@Wa1
    WsWa1f[fidx(i, t, 2)] = f2bf(a2);
  }
}

// 64 blocks x 256 threads (parallelized)
__global__ void prep2(const float* __restrict__ Wp2, const float* __restrict__ Wa2,
                      const float* __restrict__ Wa1, const float* __restrict__ bp2,
                      const float* __restrict__ ba1,
                      unsigned short* __restrict__ Wp2f, unsigned short* __restrict__ Wa2f,
                      unsigned short* __restrict__ Wp2Wa1f, float* __restrict__ bh){
  int gid = blockIdx.x * 256 + threadIdx.x;   // 0..16383
  if (gid < 8192){
    int kk = gid >> 8, c = gid & 255;
    Wp2f[fidx(kk, c, 16)] = f2bf(Wp2[gid]);
  } else {
    int g = gid - 8192; int kk = g >> 8, c = g & 255;
    Wa2f[fidx(kk, c, 16)] = f2bf(Wa2[g]);
  }
  if (gid < 1024){                     // Wp2Wa1 = Wp2@Wa1 [32][32]
    int h1 = gid >> 5, h2 = gid & 31;
    float a = 0.f;
    for (int c = 0; c < 256; ++c) a += Wp2[h1*256 + c] * Wa1[c*32 + h2];
    Wp2Wa1f[fidx(h1, h2, 2)] = f2bf(a);
  }
  if (gid < 32){                       // bh = bp2@Wa1 + ba1
    float a = ba1[gid];
    for (int c = 0; c < 256; ++c) a += bp2[c] * Wa1[c*32 + gid];
    bh[gid] = a;
  }
}

// ---------------- main kernel: phases B..E, x -> global bf16 ----------------
// Phase B (R13): lane-linear 1KB k-row loads (1 instr/row, 16 total), single
// bf16 convert stream, kh = k@W - q@W via extra q-MFMAs + one shfl broadcast
// (kills the per-element (k-q) stream: ~200 VALU + 15 loads per wave).
// Phase E: R10 proven ci-pair with NAMED accumulators.
__global__ __attribute__((amdgpu_flat_work_group_size(256,256), amdgpu_waves_per_eu(4,4)))
void attn_x(
  const float* __restrict__ q, const float* __restrict__ k,
  const float* __restrict__ pos, const int* __restrict__ mask,
  const float* __restrict__ Wp1, const float* __restrict__ bp1,
  const float* __restrict__ bp2, const float* __restrict__ bh,
  const unsigned short* __restrict__ Ws2f, const unsigned short* __restrict__ WsWa1f,
  const unsigned short* __restrict__ Wp2f, const unsigned short* __restrict__ Wa2f,
  const unsigned short* __restrict__ Wp2Wa1f,
  unsigned short* __restrict__ xbuf)
{
  __shared__ unsigned short kA[16384];  // 32 KB: [n][kt][lane][8] bf16 A-frags of k
  __shared__ unsigned short phL[2048];  // 4 KB:  [n][lane][8] pos-hidden A-frags
  __shared__ unsigned short hL[2048];   // 4 KB:  [n][lane][8] attn-hidden A-frags (q row overlaid early)

  const int t = threadIdx.x;
  const int lane = t & 63;
  const int w = t >> 6;
  const int lg = lane >> 4;
  const int lr = lane & 15;
  const int bn0 = blockIdx.x * 4;
  const int n0 = bn0 + w;
  const f4 z4 = {0.f, 0.f, 0.f, 0.f};

  // ---- Phase B: lane-linear k rows -> bf16 -> kA frag slots
  const float* kbase = k + (size_t)n0 * 4096;
  unsigned short* kAw = kA + w * 4096;
  unsigned short* qb  = hL + w * 512;   // first 256 ushorts: q row bf16 (linear)
  {
    f4 qv = *(const f4*)(q + (size_t)n0 * 256 + lane * 4);
    s4 qpk;
    qpk[0] = (short)f2bf(qv[0]); qpk[1] = (short)f2bf(qv[1]);
    qpk[2] = (short)f2bf(qv[2]); qpk[3] = (short)f2bf(qv[3]);
    *(s4*)(qb + lane * 4) = qpk;
  }
  {
    const int c0l = lane * 4;
    const int kts = c0l >> 5, lgs = (c0l >> 3) & 3, js = c0l & 7;
    unsigned short* kdst0 = kAw + ((kts * 64 + lgs * 16) << 3) + js;
    #pragma unroll
    for (int m = 0; m < 16; ++m){
      f4 kv = *(const f4*)(kbase + m * 256 + c0l);
      s4 pk;
      pk[0] = (short)f2bf(kv[0]); pk[1] = (short)f2bf(kv[1]);
      pk[2] = (short)f2bf(kv[2]); pk[3] = (short)f2bf(kv[3]);
      *(s4*)(kdst0 + (m << 3)) = pk;   // 8B store, 2 lanes/bank -> free
    }
  }

  // kh = k@WsWa1 ; qh = q@WsWa1 (row 0 valid, broadcast later)
  const unsigned short* wa1b = WsWa1f + (size_t)lane * 8;
  f4 kh0 = z4, kh1 = z4, qh0 = z4, qh1 = z4;
  #pragma unroll
  for (int kt = 0; kt < 8; ++kt){
    s8 kfr = *(const s8*)(kAw + ((kt * 64 + lane) << 3));
    s8 qfr = *(const s8*)(qb + kt * 32 + lg * 8);
    s8 wt0 = *(const s8*)(wa1b + (size_t)(kt * 2 + 0) * 512);
    s8 wt1 = *(const s8*)(wa1b + (size_t)(kt * 2 + 1) * 512);
    kh0 = MFMA16(kfr, wt0, kh0);  kh1 = MFMA16(kfr, wt1, kh1);
    qh0 = MFMA16(qfr, wt0, qh0);  qh1 = MFMA16(qfr, wt1, qh1);
  }
  float qhs0 = __shfl(qh0[0], lr);   // qh[col=lr], cols 0..15
  float qhs1 = __shfl(qh1[0], lr);   // cols 16..31

  // pos-MLP per-lane directly in A-frag layout
  s8 phfrag;
  {
    f4 pv = *(const f4*)(pos + (size_t)n0 * 64 + (size_t)lr * 4);
    f4 h0 = *(const f4*)(bp1 + lg * 8);
    f4 h1 = *(const f4*)(bp1 + lg * 8 + 4);
    #pragma unroll
    for (int p = 0; p < 4; ++p){
      f4 w0 = *(const f4*)(Wp1 + p * 32 + lg * 8);
      f4 w1 = *(const f4*)(Wp1 + p * 32 + lg * 8 + 4);
      #pragma unroll
      for (int j = 0; j < 4; ++j){ h0[j] += pv[p] * w0[j]; h1[j] += pv[p] * w1[j]; }
    }
    #pragma unroll
    for (int j = 0; j < 4; ++j){
      phfrag[j]     = (short)f2bf(fmaxf(h0[j], 0.f));
      phfrag[4 + j] = (short)f2bf(fmaxf(h1[j], 0.f));
    }
  }
  *(s8*)(phL + (w * 64 + lane) * 8) = phfrag;

  // kh += ph@Wp2Wa1
  {
    const unsigned short* wpwb = Wp2Wa1f + (size_t)lane * 8;
    kh0 = MFMA16(phfrag, *(const s8*)(wpwb), kh0);
    kh1 = MFMA16(phfrag, *(const s8*)(wpwb + 512), kh1);
  }

  // h = relu(kh - qh + bh) scattered into hL A-frag slots (overwrites qb region)
  #pragma unroll
  for (int ct2 = 0; ct2 < 2; ++ct2){
    float bhc = bh[ct2 * 16 + lr] - (ct2 ? qhs1 : qhs0);
    #pragma unroll
    for (int r = 0; r < 4; ++r){
      int m = lg * 4 + r, col = ct2 * 16 + lr;
      float hv = (ct2 ? kh1[r] : kh0[r]) + bhc;
      hL[w * 512 + ((col >> 3) * 16 + m) * 8 + (col & 7)] = f2bf(fmaxf(hv, 0.f));
    }
  }
  __syncthreads();

  // ---- Phase E: column-split with ci-pairs, NAMED accumulators, macro epilogue.
  const unsigned short* ws2b = Ws2f + (size_t)lane * 8;
  const unsigned short* wp2b = Wp2f + (size_t)lane * 8;
  const unsigned short* wa2b = Wa2f + (size_t)lane * 8;

#define EPI_N(VN, N, CT, BP, BA, BP2C) { \
    s8 pfr = *(const s8*)(phL + ((N) * 64 + lane) * 8); \
    s8 hfr = *(const s8*)(hL + ((N) * 64 + lane) * 8); \
    f4 pf = MFMA16(pfr, (BP), z4); \
    f4 aa = MFMA16(hfr, (BA), z4); \
    i4 mv = *(const i4*)(mask + (size_t)(bn0 + (N)) * 16 + lg * 4); \
    float lg0 = mv[0] ? aa[0] : -1e9f; \
    float lg1 = mv[1] ? aa[1] : -1e9f; \
    float lg2 = mv[2] ? aa[2] : -1e9f; \
    float lg3 = mv[3] ? aa[3] : -1e9f; \
    float mx = fmaxf(fmaxf(lg0, lg1), fmaxf(lg2, lg3)); \
    mx = fmaxf(mx, __shfl_xor(mx, 16)); \
    mx = fmaxf(mx, __shfl_xor(mx, 32)); \
    float p0 = __expf(lg0 - mx), p1 = __expf(lg1 - mx); \
    float p2 = __expf(lg2 - mx), p3 = __expf(lg3 - mx); \
    float den = p0 + p1 + p2 + p3; \
    float num = p0 * ((VN)[0] + pf[0] + (BP2C)) \
              + p1 * ((VN)[1] + pf[1] + (BP2C)) \
              + p2 * ((VN)[2] + pf[2] + (BP2C)) \
              + p3 * ((VN)[3] + pf[3] + (BP2C)); \
    den += __shfl_xor(den, 16); den += __shfl_xor(den, 32); \
    num += __shfl_xor(num, 16); num += __shfl_xor(num, 32); \
    if (lane < 16) \
      xbuf[(size_t)(bn0 + (N)) * 256 + (CT) * 16 + lr] = f2bf(__fdividef(num, den)); \
  }

#define EPILOGUE(V0, V1, V2, V3, CT) { \
    s8 bp = *(const s8*)(wp2b + (size_t)(CT) * 512); \
    s8 ba = *(const s8*)(wa2b + (size_t)(CT) * 512); \
    float bp2c = bp2[(CT) * 16 + lr]; \
    EPI_N(V0, 0, CT, bp, ba, bp2c); \
    EPI_N(V1, 1, CT, bp, ba, bp2c); \
    EPI_N(V2, 2, CT, bp, ba, bp2c); \
    EPI_N(V3, 3, CT, bp, ba, bp2c); \
  }

  #pragma unroll
  for (int cp = 0; cp < 2; ++cp){
    const int ct0 = w * 4 + cp * 2;
    const int ct1 = ct0 + 1;
    f4 v00 = z4, v01 = z4, v02 = z4, v03 = z4;   // ct0, n=0..3
    f4 v10 = z4, v11 = z4, v12 = z4, v13 = z4;   // ct1, n=0..3
    #pragma unroll
    for (int kt = 0; kt < 8; ++kt){
      s8 b0 = *(const s8*)(ws2b + (size_t)(kt * 16 + ct0) * 512);
      s8 b1 = *(const s8*)(ws2b + (size_t)(kt * 16 + ct1) * 512);
      s8 af0 = *(const s8*)(kA + ((0 * 8 + kt) * 64 + lane) * 8);
      s8 af1 = *(const s8*)(kA + ((1 * 8 + kt) * 64 + lane) * 8);
      s8 af2 = *(const s8*)(kA + ((2 * 8 + kt) * 64 + lane) * 8);
      s8 af3 = *(const s8*)(kA + ((3 * 8 + kt) * 64 + lane) * 8);
      v00 = MFMA16(af0, b0, v00); v10 = MFMA16(af0, b1, v10);
      v01 = MFMA16(af1, b0, v01); v11 = MFMA16(af1, b1, v11);
      v02 = MFMA16(af2, b0, v02); v12 = MFMA16(af2, b1, v12);
      v03 = MFMA16(af3, b0, v03); v13 = MFMA16(af3, b1, v13);
    }
    EPILOGUE(v00, v01, v02, v03, ct0);
    EPILOGUE(v10, v11, v12, v13, ct1);
  }
#undef EPILOGUE
#undef EPI_N
}

// ---------------- proj kernel: out = x @ Wo + bo ----------------
__global__ __launch_bounds__(128, 4) void proj(
  const unsigned short* __restrict__ xbuf, const unsigned short* __restrict__ Wof,
  const float* __restrict__ bo, float* __restrict__ out)
{
  const int t = threadIdx.x;
  const int lane = t & 63;
  const int w = t >> 6;
  const int lg = lane >> 4;
  const int lr = lane & 15;
  const int n0 = blockIdx.x * 32 + w * 16;
  const f4 z4 = {0.f, 0.f, 0.f, 0.f};
  const unsigned short* xr = xbuf + (size_t)(n0 + lr) * 256;
  const unsigned short* wob = Wof + (size_t)lane * 8;
  #pragma unroll
  for (int p = 0; p < 4; ++p){
    f4 oac[4] = {z4, z4, z4, z4};
    #pragma unroll
    for (int kt = 0; kt < 8; ++kt){
      s8 xf = *(const s8*)(xr + kt * 32 + lg * 8);
      #pragma unroll
      for (int ci = 0; ci < 4; ++ci)
        oac[ci] = MFMA16(xf, *(const s8*)(wob + (size_t)(kt * 16 + p * 4 + ci) * 512), oac[ci]);
    }
    #pragma unroll
    for (int ci = 0; ci < 4; ++ci){
      int c = (p * 4 + ci) * 16 + lr;
      float bov = bo[c];
      #pragma unroll
      for (int r = 0; r < 4; ++r)
        out[(size_t)(n0 + lg * 4 + r) * 256 + c] = oac[ci][r] + bov;
    }
  }
}

// ---------------- fallback monolithic kernel (R4, proven) ----------------
__global__ __launch_bounds__(256, 4) void attn_mono(
  const float* __restrict__ q, const float* __restrict__ k,
  const float* __restrict__ pos, const int* __restrict__ mask,
  const float* __restrict__ Wp1, const float* __restrict__ bp1,
  const float* __restrict__ bp2, const float* __restrict__ bo,
  const float* __restrict__ bh,
  const unsigned short* __restrict__ Ws2f, const unsigned short* __restrict__ WsWa1f,
  const unsigned short* __restrict__ Wp2f, const unsigned short* __restrict__ Wa2f,
  const unsigned short* __restrict__ Wp2Wa1f, const unsigned short* __restrict__ Wof,
  float* __restrict__ out)
{
  __shared__ unsigned short kA[16384];
  __shared__ unsigned short phL[2048];
  __shared__ unsigned short hL[2048];
  __shared__ unsigned short xT[4096];

  const int t = threadIdx.x;
  const int lane = t & 63;
  const int w = t >> 6;
  const int lg = lane >> 4;
  const int lr = lane & 15;
  const int bn0 = blockIdx.x * 4;
  const int n0 = bn0 + w;
  const f4 z4 = {0.f, 0.f, 0.f, 0.f};

  const float* krow = k + (size_t)n0 * 4096 + (size_t)lr * 256;
  const float* qrow = q + (size_t)n0 * 256;
  const unsigned short* wa1b = WsWa1f + (size_t)lane * 8;
  f4 khac[2] = {z4, z4};
  #pragma unroll
  for (int kt = 0; kt < 8; ++kt){
    int c0 = kt * 32 + lg * 8;
    f4 ka = *(const f4*)(krow + c0);
    f4 kb = *(const f4*)(krow + c0 + 4);
    f4 qa = *(const f4*)(qrow + c0);
    f4 qb = *(const f4*)(qrow + c0 + 4);
    s8 kf, mf;
    #pragma unroll
    for (int j = 0; j < 4; ++j){
      kf[j]     = (short)f2bf(ka[j]);
      kf[4 + j] = (short)f2bf(kb[j]);
      mf[j]     = (short)f2bf(ka[j] - qa[j]);
      mf[4 + j] = (short)f2bf(kb[j] - qb[j]);
    }
    *(s8*)(kA + ((w * 8 + kt) * 64 + lane) * 8) = kf;
    khac[0] = MFMA16(mf, *(const s8*)(wa1b + (size_t)(kt * 2 + 0) * 512), khac[0]);
    khac[1] = MFMA16(mf, *(const s8*)(wa1b + (size_t)(kt * 2 + 1) * 512), khac[1]);
  }
  s8 phfrag;
  {
    f4 pv = *(const f4*)(pos + (size_t)n0 * 64 + (size_t)lr * 4);
    f4 h0 = *(const f4*)(bp1 + lg * 8);
    f4 h1 = *(const f4*)(bp1 + lg * 8 + 4);
    #pragma unroll
    for (int p = 0; p < 4; ++p){
      f4 w0 = *(const f4*)(Wp1 + p * 32 + lg * 8);
      f4 w1 = *(const f4*)(Wp1 + p * 32 + lg * 8 + 4);
      #pragma unroll
      for (int j = 0; j < 4; ++j){ h0[j] += pv[p] * w0[j]; h1[j] += pv[p] * w1[j]; }
    }
    #pragma unroll
    for (int j = 0; j < 4; ++j){
      phfrag[j]     = (short)f2bf(fmaxf(h0[j], 0.f));
      phfrag[4 + j] = (short)f2bf(fmaxf(h1[j], 0.f));
    }
  }
  *(s8*)(phL + (w * 64 + lane) * 8) = phfrag;
  {
    const unsigned short* wpwb = Wp2Wa1f + (size_t)lane * 8;
    khac[0] = MFMA16(phfrag, *(const s8*)(wpwb), khac[0]);
    khac[1] = MFMA16(phfrag, *(const s8*)(wpwb + 512), khac[1]);
  }
  #pragma unroll
  for (int ct2 = 0; ct2 < 2; ++ct2){
    float bhc = bh[ct2 * 16 + lr];
    #pragma unroll
    for (int r = 0; r < 4; ++r){
      int m = lg * 4 + r, col = ct2 * 16 + lr;
      hL[w * 512 + ((col >> 3) * 16 + m) * 8 + (col & 7)] = f2bf(fmaxf(khac[ct2][r] + bhc, 0.f));
    }
  }
  __syncthreads();

  const unsigned short* ws2b = Ws2f + (size_t)lane * 8;
  const unsigned short* wp2b = Wp2f + (size_t)lane * 8;
  const unsigned short* wa2b = Wa2f + (size_t)lane * 8;
  #pragma unroll
  for (int ci = 0; ci < 4; ++ci){
    int ct = w * 4 + ci;
    f4 vacc[4] = {z4, z4, z4, z4};
    #pragma unroll
    for (int kt = 0; kt < 8; ++kt){
      s8 bw = *(const s8*)(ws2b + (size_t)(kt * 16 + ct) * 512);
      #pragma unroll
      for (int n = 0; n < 4; ++n){
        s8 af = *(const s8*)(kA + ((n * 8 + kt) * 64 + lane) * 8);
        vacc[n] = MFMA16(af, bw, vacc[n]);
      }
    }
    s8 bp = *(const s8*)(wp2b + (size_t)ct * 512);
    s8 ba = *(const s8*)(wa2b + (size_t)ct * 512);
    f4 pf[4], aa[4];
    #pragma unroll
    for (int n = 0; n < 4; ++n){
      s8 pfr = *(const s8*)(phL + (n * 64 + lane) * 8);
      s8 hfr = *(const s8*)(hL + (n * 64 + lane) * 8);
      pf[n] = MFMA16(pfr, bp, z4);
      aa[n] = MFMA16(hfr, ba, z4);
    }
    float bp2c = bp2[ct * 16 + lr];
    #pragma unroll
    for (int n = 0; n < 4; ++n){
      i4 mv = *(const i4*)(mask + (size_t)(bn0 + n) * 16 + lg * 4);
      float lg0 = mv[0] ? aa[n][0] : -1e9f;
      float lg1 = mv[1] ? aa[n][1] : -1e9f;
      float lg2 = mv[2] ? aa[n][2] : -1e9f;
      float lg3 = mv[3] ? aa[n][3] : -1e9f;
      float mx = fmaxf(fmaxf(lg0, lg1), fmaxf(lg2, lg3));
      mx = fmaxf(mx, __shfl_xor(mx, 16));
      mx = fmaxf(mx, __shfl_xor(mx, 32));
      float p0 = __expf(lg0 - mx), p1 = __expf(lg1 - mx);
      float p2 = __expf(lg2 - mx), p3 = __expf(lg3 - mx);
      float den = p0 + p1 + p2 + p3;
      float num = p0 * (vacc[n][0] + pf[n][0] + bp2c)
                + p1 * (vacc[n][1] + pf[n][1] + bp2c)
                + p2 * (vacc[n][2] + pf[n][2] + bp2c)
                + p3 * (vacc[n][3] + pf[n][3] + bp2c);
      den += __shfl_xor(den, 16); den += __shfl_xor(den, 32);
      num += __shfl_xor(num, 16); num += __shfl_xor(num, 32);
      if (lane < 16){
        int c = ct * 16 + lr;
        xT[((c >> 5) * 64 + ((c >> 3) & 3) * 16 + n) * 8 + (c & 7)] = f2bf(__fdividef(num, den));
      }
    }
  }
  __syncthreads();

  f4 oac[4] = {z4, z4, z4, z4};
  const unsigned short* wob = Wof + (size_t)lane * 8;
  #pragma unroll
  for (int kt = 0; kt < 8; ++kt){
    s8 xf = *(const s8*)(xT + (kt * 64 + lane) * 8);
    #pragma unroll
    for (int ci = 0; ci < 4; ++ci)
      oac[ci] = MFMA16(xf, *(const s8*)(wob + (size_t)(kt * 16 + w * 4 + ci) * 512), oac[ci]);
  }
  if (lane < 16){
    #pragma unroll
    for (int ci = 0; ci < 4; ++ci){
      int c = (w * 4 + ci) * 16 + lr;
      float bov = bo[c];
      #pragma unroll
      for (int r = 0; r < 4; ++r)
        out[(size_t)(bn0 + r) * 256 + c] = oac[ci][r] + bov;
    }
  }
}

extern "C" void kernel_launch(void* const* d_in, const int* in_sizes, int n_in,
                              void* d_out, int out_size, void* d_ws, size_t ws_size,
                              hipStream_t stream) {
  (void)in_sizes; (void)n_in; (void)out_size;
  const float* q   = (const float*)d_in[0];
  const float* k   = (const float*)d_in[1];
  const float* pos = (const float*)d_in[2];
  const int*   msk = (const int*)d_in[3];
  const float* Ws  = (const float*)d_in[4];
  const float* Wp1 = (const float*)d_in[5];
  const float* bp1 = (const float*)d_in[6];
  const float* Wp2 = (const float*)d_in[7];
  const float* bp2 = (const float*)d_in[8];
  const float* Wa1 = (const float*)d_in[9];
  const float* ba1 = (const float*)d_in[10];
  const float* Wa2 = (const float*)d_in[11];
  // d_in[12] = ba2: constant along softmax axis -> mathematically a no-op
  const float* Wo  = (const float*)d_in[13];
  const float* bo  = (const float*)d_in[14];

  if (ws_size < 313472) return;
  char* ws = (char*)d_ws;
  unsigned short* Ws2f    = (unsigned short*)(ws + 0);       // 131072 B
  unsigned short* Wof     = (unsigned short*)(ws + 131072);  // 131072 B
  unsigned short* WsWa1f  = (unsigned short*)(ws + 262144);  // 16384 B
  unsigned short* Wp2f    = (unsigned short*)(ws + 278528);  // 16384 B
  unsigned short* Wa2f    = (unsigned short*)(ws + 294912);  // 16384 B
  unsigned short* Wp2Wa1f = (unsigned short*)(ws + 311296);  // 2048 B
  float*          bh      = (float*)(ws + 313344);           // 128 B
  unsigned short* xbuf    = (unsigned short*)(ws + 313472);  // 8388608 B

  prep1<<<dim3(256), dim3(256), 0, stream>>>(Ws, Wa1, Wo, Ws2f, Wof, WsWa1f);
  prep2<<<dim3(64), dim3(256), 0, stream>>>(Wp2, Wa2, Wa1, bp2, ba1, Wp2f, Wa2f, Wp2Wa1f, bh);

  if (ws_size >= 313472 + 8388608) {
    attn_x<<<dim3(4096), dim3(256), 0, stream>>>(q, k, pos, msk, Wp1, bp1, bp2, bh,
                                                 Ws2f, WsWa1f, Wp2f, Wa2f, Wp2Wa1f, xbuf);
    proj<<<dim3(512), dim3(128), 0, stream>>>(xbuf, Wof, bo, (float*)d_out);
  } else {
    attn_mono<<<dim3(4096), dim3(256), 0, stream>>>(q, k, pos, msk, Wp1, bp1, bp2, bo, bh,
                                                    Ws2f, WsWa1f, Wp2f, Wa2f, Wp2Wa1f, Wof,
                                                    (float*)d_out);
  }
}

// Round 14
// 149.939 us; speedup vs baseline: 1.1767x; 1.0495x over previous
//
#include <hip/hip_runtime.h>
#include <hip/hip_bf16.h>

typedef __attribute__((ext_vector_type(4))) float f4;
typedef __attribute__((ext_vector_type(4))) int i4;
typedef __attribute__((ext_vector_type(8))) short s8;
typedef __attribute__((ext_vector_type(4))) short s4;

#define MFMA16(a,b,c) __builtin_amdgcn_mfma_f32_16x16x32_bf16((a),(b),(c),0,0,0)

static __device__ __forceinline__ unsigned short f2bf(float x){
  return __builtin_bit_cast(unsigned short, __float2bfloat16(x));
}
// B-fragment-linear index for mfma_f32_16x16x32_bf16:
// lane l holds B[k = kt*32 + (l>>4)*8 + j][col = ct*16 + (l&15)], j=0..7
__device__ __forceinline__ int fidx(int kk, int c, int nct){
  return ((((kk >> 5) * nct + (c >> 4)) << 6) + (((kk >> 3) & 3) * 16 + (c & 15))) * 8 + (kk & 7);
}

// ---------------- merged prep kernel: blocks 0..255 = prep1, 256..319 = prep2 ----------------
__global__ void prepw(const float* __restrict__ Ws, const float* __restrict__ Wa1,
                      const float* __restrict__ Wo, const float* __restrict__ Wp2,
                      const float* __restrict__ Wa2, const float* __restrict__ bp2,
                      const float* __restrict__ ba1,
                      unsigned short* __restrict__ Ws2f, unsigned short* __restrict__ Wof,
                      unsigned short* __restrict__ WsWa1f,
                      unsigned short* __restrict__ Wp2f, unsigned short* __restrict__ Wa2f,
                      unsigned short* __restrict__ Wp2Wa1f, float* __restrict__ bh){
  __shared__ float wrow[256];
  int t = threadIdx.x;
  if (blockIdx.x < 256){
    int i = blockIdx.x;
    wrow[t] = Ws[i*256 + t];
    __syncthreads();
    float a1 = 0.f;
    for (int t2 = 0; t2 < 256; ++t2) a1 += wrow[t2] * Ws[t2*256 + t];   // Ws2 = Ws@Ws
    Ws2f[fidx(i, t, 16)] = f2bf(a1);
    Wof[fidx(i, t, 16)]  = f2bf(Wo[i*256 + t]);
    if (t < 32){
      float a2 = 0.f;
      for (int t2 = 0; t2 < 256; ++t2) a2 += wrow[t2] * Wa1[t2*32 + t]; // WsWa1 = Ws@Wa1
      WsWa1f[fidx(i, t, 2)] = f2bf(a2);
    }
  } else {
    int gid = (blockIdx.x - 256) * 256 + t;   // 0..16383
    if (gid < 8192){
      int kk = gid >> 8, c = gid & 255;
      Wp2f[fidx(kk, c, 16)] = f2bf(Wp2[gid]);
    } else {
      int g = gid - 8192; int kk = g >> 8, c = g & 255;
      Wa2f[fidx(kk, c, 16)] = f2bf(Wa2[g]);
    }
    if (gid < 1024){                     // Wp2Wa1 = Wp2@Wa1 [32][32]
      int h1 = gid >> 5, h2 = gid & 31;
      float a = 0.f;
      for (int c = 0; c < 256; ++c) a += Wp2[h1*256 + c] * Wa1[c*32 + h2];
      Wp2Wa1f[fidx(h1, h2, 2)] = f2bf(a);
    }
    if (gid < 32){                       // bh = bp2@Wa1 + ba1
      float a = ba1[gid];
      for (int c = 0; c < 256; ++c) a += bp2[c] * Wa1[c*32 + gid];
      bh[gid] = a;
    }
  }
}

// ---------------- main kernel: phases B..E, x -> global bf16 (R13 proven) ----------------
// Phase B: lane-linear 1KB k-row loads (1 instr/row, 16 total), single bf16
// convert stream, kh = k@W - q@W via extra q-MFMAs + one shfl broadcast.
// Phase E: ci-pair with NAMED accumulators (arrays/lambda-pointers spill).
__global__ __attribute__((amdgpu_flat_work_group_size(256,256), amdgpu_waves_per_eu(4,4)))
void attn_x(
  const float* __restrict__ q, const float* __restrict__ k,
  const float* __restrict__ pos, const int* __restrict__ mask,
  const float* __restrict__ Wp1, const float* __restrict__ bp1,
  const float* __restrict__ bp2, const float* __restrict__ bh,
  const unsigned short* __restrict__ Ws2f, const unsigned short* __restrict__ WsWa1f,
  const unsigned short* __restrict__ Wp2f, const unsigned short* __restrict__ Wa2f,
  const unsigned short* __restrict__ Wp2Wa1f,
  unsigned short* __restrict__ xbuf)
{
  __shared__ unsigned short kA[16384];  // 32 KB: [n][kt][lane][8] bf16 A-frags of k
  __shared__ unsigned short phL[2048];  // 4 KB:  [n][lane][8] pos-hidden A-frags
  __shared__ unsigned short hL[2048];   // 4 KB:  [n][lane][8] attn-hidden A-frags (q row overlaid early)

  const int t = threadIdx.x;
  const int lane = t & 63;
  const int w = t >> 6;
  const int lg = lane >> 4;
  const int lr = lane & 15;
  const int bn0 = blockIdx.x * 4;
  const int n0 = bn0 + w;
  const f4 z4 = {0.f, 0.f, 0.f, 0.f};

  // ---- Phase B: lane-linear k rows -> bf16 -> kA frag slots
  const float* kbase = k + (size_t)n0 * 4096;
  unsigned short* kAw = kA + w * 4096;
  unsigned short* qb  = hL + w * 512;   // first 256 ushorts: q row bf16 (linear)
  {
    f4 qv = *(const f4*)(q + (size_t)n0 * 256 + lane * 4);
    s4 qpk;
    qpk[0] = (short)f2bf(qv[0]); qpk[1] = (short)f2bf(qv[1]);
    qpk[2] = (short)f2bf(qv[2]); qpk[3] = (short)f2bf(qv[3]);
    *(s4*)(qb + lane * 4) = qpk;
  }
  {
    const int c0l = lane * 4;
    const int kts = c0l >> 5, lgs = (c0l >> 3) & 3, js = c0l & 7;
    unsigned short* kdst0 = kAw + ((kts * 64 + lgs * 16) << 3) + js;
    #pragma unroll
    for (int m = 0; m < 16; ++m){
      f4 kv = *(const f4*)(kbase + m * 256 + c0l);
      s4 pk;
      pk[0] = (short)f2bf(kv[0]); pk[1] = (short)f2bf(kv[1]);
      pk[2] = (short)f2bf(kv[2]); pk[3] = (short)f2bf(kv[3]);
      *(s4*)(kdst0 + (m << 3)) = pk;   // 8B store, 2 lanes/bank -> free
    }
  }

  // kh = k@WsWa1 ; qh = q@WsWa1 (row 0 valid, broadcast later)
  const unsigned short* wa1b = WsWa1f + (size_t)lane * 8;
  f4 kh0 = z4, kh1 = z4, qh0 = z4, qh1 = z4;
  #pragma unroll
  for (int kt = 0; kt < 8; ++kt){
    s8 kfr = *(const s8*)(kAw + ((kt * 64 + lane) << 3));
    s8 qfr = *(const s8*)(qb + kt * 32 + lg * 8);
    s8 wt0 = *(const s8*)(wa1b + (size_t)(kt * 2 + 0) * 512);
    s8 wt1 = *(const s8*)(wa1b + (size_t)(kt * 2 + 1) * 512);
    kh0 = MFMA16(kfr, wt0, kh0);  kh1 = MFMA16(kfr, wt1, kh1);
    qh0 = MFMA16(qfr, wt0, qh0);  qh1 = MFMA16(qfr, wt1, qh1);
  }
  float qhs0 = __shfl(qh0[0], lr);   // qh[col=lr], cols 0..15
  float qhs1 = __shfl(qh1[0], lr);   // cols 16..31

  // pos-MLP per-lane directly in A-frag layout
  s8 phfrag;
  {
    f4 pv = *(const f4*)(pos + (size_t)n0 * 64 + (size_t)lr * 4);
    f4 h0 = *(const f4*)(bp1 + lg * 8);
    f4 h1 = *(const f4*)(bp1 + lg * 8 + 4);
    #pragma unroll
    for (int p = 0; p < 4; ++p){
      f4 w0 = *(const f4*)(Wp1 + p * 32 + lg * 8);
      f4 w1 = *(const f4*)(Wp1 + p * 32 + lg * 8 + 4);
      #pragma unroll
      for (int j = 0; j < 4; ++j){ h0[j] += pv[p] * w0[j]; h1[j] += pv[p] * w1[j]; }
    }
    #pragma unroll
    for (int j = 0; j < 4; ++j){
      phfrag[j]     = (short)f2bf(fmaxf(h0[j], 0.f));
      phfrag[4 + j] = (short)f2bf(fmaxf(h1[j], 0.f));
    }
  }
  *(s8*)(phL + (w * 64 + lane) * 8) = phfrag;

  // kh += ph@Wp2Wa1
  {
    const unsigned short* wpwb = Wp2Wa1f + (size_t)lane * 8;
    kh0 = MFMA16(phfrag, *(const s8*)(wpwb), kh0);
    kh1 = MFMA16(phfrag, *(const s8*)(wpwb + 512), kh1);
  }

  // h = relu(kh - qh + bh) scattered into hL A-frag slots (overwrites qb region)
  #pragma unroll
  for (int ct2 = 0; ct2 < 2; ++ct2){
    float bhc = bh[ct2 * 16 + lr] - (ct2 ? qhs1 : qhs0);
    #pragma unroll
    for (int r = 0; r < 4; ++r){
      int m = lg * 4 + r, col = ct2 * 16 + lr;
      float hv = (ct2 ? kh1[r] : kh0[r]) + bhc;
      hL[w * 512 + ((col >> 3) * 16 + m) * 8 + (col & 7)] = f2bf(fmaxf(hv, 0.f));
    }
  }
  __syncthreads();

  // ---- Phase E: column-split with ci-pairs, NAMED accumulators, macro epilogue.
  const unsigned short* ws2b = Ws2f + (size_t)lane * 8;
  const unsigned short* wp2b = Wp2f + (size_t)lane * 8;
  const unsigned short* wa2b = Wa2f + (size_t)lane * 8;

#define EPI_N(VN, N, CT, BP, BA, BP2C) { \
    s8 pfr = *(const s8*)(phL + ((N) * 64 + lane) * 8); \
    s8 hfr = *(const s8*)(hL + ((N) * 64 + lane) * 8); \
    f4 pf = MFMA16(pfr, (BP), z4); \
    f4 aa = MFMA16(hfr, (BA), z4); \
    i4 mv = *(const i4*)(mask + (size_t)(bn0 + (N)) * 16 + lg * 4); \
    float lg0 = mv[0] ? aa[0] : -1e9f; \
    float lg1 = mv[1] ? aa[1] : -1e9f; \
    float lg2 = mv[2] ? aa[2] : -1e9f; \
    float lg3 = mv[3] ? aa[3] : -1e9f; \
    float mx = fmaxf(fmaxf(lg0, lg1), fmaxf(lg2, lg3)); \
    mx = fmaxf(mx, __shfl_xor(mx, 16)); \
    mx = fmaxf(mx, __shfl_xor(mx, 32)); \
    float p0 = __expf(lg0 - mx), p1 = __expf(lg1 - mx); \
    float p2 = __expf(lg2 - mx), p3 = __expf(lg3 - mx); \
    float den = p0 + p1 + p2 + p3; \
    float num = p0 * ((VN)[0] + pf[0] + (BP2C)) \
              + p1 * ((VN)[1] + pf[1] + (BP2C)) \
              + p2 * ((VN)[2] + pf[2] + (BP2C)) \
              + p3 * ((VN)[3] + pf[3] + (BP2C)); \
    den += __shfl_xor(den, 16); den += __shfl_xor(den, 32); \
    num += __shfl_xor(num, 16); num += __shfl_xor(num, 32); \
    if (lane < 16) \
      xbuf[(size_t)(bn0 + (N)) * 256 + (CT) * 16 + lr] = f2bf(__fdividef(num, den)); \
  }

#define EPILOGUE(V0, V1, V2, V3, CT) { \
    s8 bp = *(const s8*)(wp2b + (size_t)(CT) * 512); \
    s8 ba = *(const s8*)(wa2b + (size_t)(CT) * 512); \
    float bp2c = bp2[(CT) * 16 + lr]; \
    EPI_N(V0, 0, CT, bp, ba, bp2c); \
    EPI_N(V1, 1, CT, bp, ba, bp2c); \
    EPI_N(V2, 2, CT, bp, ba, bp2c); \
    EPI_N(V3, 3, CT, bp, ba, bp2c); \
  }

  #pragma unroll
  for (int cp = 0; cp < 2; ++cp){
    const int ct0 = w * 4 + cp * 2;
    const int ct1 = ct0 + 1;
    f4 v00 = z4, v01 = z4, v02 = z4, v03 = z4;   // ct0, n=0..3
    f4 v10 = z4, v11 = z4, v12 = z4, v13 = z4;   // ct1, n=0..3
    #pragma unroll
    for (int kt = 0; kt < 8; ++kt){
      s8 b0 = *(const s8*)(ws2b + (size_t)(kt * 16 + ct0) * 512);
      s8 b1 = *(const s8*)(ws2b + (size_t)(kt * 16 + ct1) * 512);
      s8 af0 = *(const s8*)(kA + ((0 * 8 + kt) * 64 + lane) * 8);
      s8 af1 = *(const s8*)(kA + ((1 * 8 + kt) * 64 + lane) * 8);
      s8 af2 = *(const s8*)(kA + ((2 * 8 + kt) * 64 + lane) * 8);
      s8 af3 = *(const s8*)(kA + ((3 * 8 + kt) * 64 + lane) * 8);
      v00 = MFMA16(af0, b0, v00); v10 = MFMA16(af0, b1, v10);
      v01 = MFMA16(af1, b0, v01); v11 = MFMA16(af1, b1, v11);
      v02 = MFMA16(af2, b0, v02); v12 = MFMA16(af2, b1, v12);
      v03 = MFMA16(af3, b0, v03); v13 = MFMA16(af3, b1, v13);
    }
    EPILOGUE(v00, v01, v02, v03, ct0);
    EPILOGUE(v10, v11, v12, v13, ct1);
  }
#undef EPILOGUE
#undef EPI_N
}

// ---------------- proj kernel: out = x @ Wo + bo ----------------
__global__ __launch_bounds__(128, 4) void proj(
  const unsigned short* __restrict__ xbuf, const unsigned short* __restrict__ Wof,
  const float* __restrict__ bo, float* __restrict__ out)
{
  const int t = threadIdx.x;
  const int lane = t & 63;
  const int w = t >> 6;
  const int lg = lane >> 4;
  const int lr = lane & 15;
  const int n0 = blockIdx.x * 32 + w * 16;
  const f4 z4 = {0.f, 0.f, 0.f, 0.f};
  const unsigned short* xr = xbuf + (size_t)(n0 + lr) * 256;
  const unsigned short* wob = Wof + (size_t)lane * 8;
  #pragma unroll
  for (int p = 0; p < 4; ++p){
    f4 oac[4] = {z4, z4, z4, z4};
    #pragma unroll
    for (int kt = 0; kt < 8; ++kt){
      s8 xf = *(const s8*)(xr + kt * 32 + lg * 8);
      #pragma unroll
      for (int ci = 0; ci < 4; ++ci)
        oac[ci] = MFMA16(xf, *(const s8*)(wob + (size_t)(kt * 16 + p * 4 + ci) * 512), oac[ci]);
    }
    #pragma unroll
    for (int ci = 0; ci < 4; ++ci){
      int c = (p * 4 + ci) * 16 + lr;
      float bov = bo[c];
      #pragma unroll
      for (int r = 0; r < 4; ++r)
        out[(size_t)(n0 + lg * 4 + r) * 256 + c] = oac[ci][r] + bov;
    }
  }
}

// ---------------- fallback monolithic kernel (R4, proven) ----------------
__global__ __launch_bounds__(256, 4) void attn_mono(
  const float* __restrict__ q, const float* __restrict__ k,
  const float* __restrict__ pos, const int* __restrict__ mask,
  const float* __restrict__ Wp1, const float* __restrict__ bp1,
  const float* __restrict__ bp2, const float* __restrict__ bo,
  const float* __restrict__ bh,
  const unsigned short* __restrict__ Ws2f, const unsigned short* __restrict__ WsWa1f,
  const unsigned short* __restrict__ Wp2f, const unsigned short* __restrict__ Wa2f,
  const unsigned short* __restrict__ Wp2Wa1f, const unsigned short* __restrict__ Wof,
  float* __restrict__ out)
{
  __shared__ unsigned short kA[16384];
  __shared__ unsigned short phL[2048];
  __shared__ unsigned short hL[2048];
  __shared__ unsigned short xT[4096];

  const int t = threadIdx.x;
  const int lane = t & 63;
  const int w = t >> 6;
  const int lg = lane >> 4;
  const int lr = lane & 15;
  const int bn0 = blockIdx.x * 4;
  const int n0 = bn0 + w;
  const f4 z4 = {0.f, 0.f, 0.f, 0.f};

  const float* krow = k + (size_t)n0 * 4096 + (size_t)lr * 256;
  const float* qrow = q + (size_t)n0 * 256;
  const unsigned short* wa1b = WsWa1f + (size_t)lane * 8;
  f4 khac[2] = {z4, z4};
  #pragma unroll
  for (int kt = 0; kt < 8; ++kt){
    int c0 = kt * 32 + lg * 8;
    f4 ka = *(const f4*)(krow + c0);
    f4 kb = *(const f4*)(krow + c0 + 4);
    f4 qa = *(const f4*)(qrow + c0);
    f4 qb = *(const f4*)(qrow + c0 + 4);
    s8 kf, mf;
    #pragma unroll
    for (int j = 0; j < 4; ++j){
      kf[j]     = (short)f2bf(ka[j]);
      kf[4 + j] = (short)f2bf(kb[j]);
      mf[j]     = (short)f2bf(ka[j] - qa[j]);
      mf[4 + j] = (short)f2bf(kb[j] - qb[j]);
    }
    *(s8*)(kA + ((w * 8 + kt) * 64 + lane) * 8) = kf;
    khac[0] = MFMA16(mf, *(const s8*)(wa1b + (size_t)(kt * 2 + 0) * 512), khac[0]);
    khac[1] = MFMA16(mf, *(const s8*)(wa1b + (size_t)(kt * 2 + 1) * 512), khac[1]);
  }
  s8 phfrag;
  {
    f4 pv = *(const f4*)(pos + (size_t)n0 * 64 + (size_t)lr * 4);
    f4 h0 = *(const f4*)(bp1 + lg * 8);
    f4 h1 = *(const f4*)(bp1 + lg * 8 + 4);
    #pragma unroll
    for (int p = 0; p < 4; ++p){
      f4 w0 = *(const f4*)(Wp1 + p * 32 + lg * 8);
      f4 w1 = *(const f4*)(Wp1 + p * 32 + lg * 8 + 4);
      #pragma unroll
      for (int j = 0; j < 4; ++j){ h0[j] += pv[p] * w0[j]; h1[j] += pv[p] * w1[j]; }
    }
    #pragma unroll
    for (int j = 0; j < 4; ++j){
      phfrag[j]     = (short)f2bf(fmaxf(h0[j], 0.f));
      phfrag[4 + j] = (short)f2bf(fmaxf(h1[j], 0.f));
    }
  }
  *(s8*)(phL + (w * 64 + lane) * 8) = phfrag;
  {
    const unsigned short* wpwb = Wp2Wa1f + (size_t)lane * 8;
    khac[0] = MFMA16(phfrag, *(const s8*)(wpwb), khac[0]);
    khac[1] = MFMA16(phfrag, *(const s8*)(wpwb + 512), khac[1]);
  }
  #pragma unroll
  for (int ct2 = 0; ct2 < 2; ++ct2){
    float bhc = bh[ct2 * 16 + lr];
    #pragma unroll
    for (int r = 0; r < 4; ++r){
      int m = lg * 4 + r, col = ct2 * 16 + lr;
      hL[w * 512 + ((col >> 3) * 16 + m) * 8 + (col & 7)] = f2bf(fmaxf(khac[ct2][r] + bhc, 0.f));
    }
  }
  __syncthreads();

  const unsigned short* ws2b = Ws2f + (size_t)lane * 8;
  const unsigned short* wp2b = Wp2f + (size_t)lane * 8;
  const unsigned short* wa2b = Wa2f + (size_t)lane * 8;
  #pragma unroll
  for (int ci = 0; ci < 4; ++ci){
    int ct = w * 4 + ci;
    f4 vacc[4] = {z4, z4, z4, z4};
    #pragma unroll
    for (int kt = 0; kt < 8; ++kt){
      s8 bw = *(const s8*)(ws2b + (size_t)(kt * 16 + ct) * 512);
      #pragma unroll
      for (int n = 0; n < 4; ++n){
        s8 af = *(const s8*)(kA + ((n * 8 + kt) * 64 + lane) * 8);
        vacc[n] = MFMA16(af, bw, vacc[n]);
      }
    }
    s8 bp = *(const s8*)(wp2b + (size_t)ct * 512);
    s8 ba = *(const s8*)(wa2b + (size_t)ct * 512);
    f4 pf[4], aa[4];
    #pragma unroll
    for (int n = 0; n < 4; ++n){
      s8 pfr = *(const s8*)(phL + (n * 64 + lane) * 8);
      s8 hfr = *(const s8*)(hL + (n * 64 + lane) * 8);
      pf[n] = MFMA16(pfr, bp, z4);
      aa[n] = MFMA16(hfr, ba, z4);
    }
    float bp2c = bp2[ct * 16 + lr];
    #pragma unroll
    for (int n = 0; n < 4; ++n){
      i4 mv = *(const i4*)(mask + (size_t)(bn0 + n) * 16 + lg * 4);
      float lg0 = mv[0] ? aa[n][0] : -1e9f;
      float lg1 = mv[1] ? aa[n][1] : -1e9f;
      float lg2 = mv[2] ? aa[n][2] : -1e9f;
      float lg3 = mv[3] ? aa[n][3] : -1e9f;
      float mx = fmaxf(fmaxf(lg0, lg1), fmaxf(lg2, lg3));
      mx = fmaxf(mx, __shfl_xor(mx, 16));
      mx = fmaxf(mx, __shfl_xor(mx, 32));
      float p0 = __expf(lg0 - mx), p1 = __expf(lg1 - mx);
      float p2 = __expf(lg2 - mx), p3 = __expf(lg3 - mx);
      float den = p0 + p1 + p2 + p3;
      float num = p0 * (vacc[n][0] + pf[n][0] + bp2c)
                + p1 * (vacc[n][1] + pf[n][1] + bp2c)
                + p2 * (vacc[n][2] + pf[n][2] + bp2c)
                + p3 * (vacc[n][3] + pf[n][3] + bp2c);
      den += __shfl_xor(den, 16); den += __shfl_xor(den, 32);
      num += __shfl_xor(num, 16); num += __shfl_xor(num, 32);
      if (lane < 16){
        int c = ct * 16 + lr;
        xT[((c >> 5) * 64 + ((c >> 3) & 3) * 16 + n) * 8 + (c & 7)] = f2bf(__fdividef(num, den));
      }
    }
  }
  __syncthreads();

  f4 oac[4] = {z4, z4, z4, z4};
  const unsigned short* wob = Wof + (size_t)lane * 8;
  #pragma unroll
  for (int kt = 0; kt < 8; ++kt){
    s8 xf = *(const s8*)(xT + (kt * 64 + lane) * 8);
    #pragma unroll
    for (int ci = 0; ci < 4; ++ci)
      oac[ci] = MFMA16(xf, *(const s8*)(wob + (size_t)(kt * 16 + w * 4 + ci) * 512), oac[ci]);
  }
  if (lane < 16){
    #pragma unroll
    for (int ci = 0; ci < 4; ++ci){
      int c = (w * 4 + ci) * 16 + lr;
      float bov = bo[c];
      #pragma unroll
      for (int r = 0; r < 4; ++r)
        out[(size_t)(bn0 + r) * 256 + c] = oac[ci][r] + bov;
    }
  }
}

extern "C" void kernel_launch(void* const* d_in, const int* in_sizes, int n_in,
                              void* d_out, int out_size, void* d_ws, size_t ws_size,
                              hipStream_t stream) {
  (void)in_sizes; (void)n_in; (void)out_size;
  const float* q   = (const float*)d_in[0];
  const float* k   = (const float*)d_in[1];
  const float* pos = (const float*)d_in[2];
  const int*   msk = (const int*)d_in[3];
  const float* Ws  = (const float*)d_in[4];
  const float* Wp1 = (const float*)d_in[5];
  const float* bp1 = (const float*)d_in[6];
  const float* Wp2 = (const float*)d_in[7];
  const float* bp2 = (const float*)d_in[8];
  const float* Wa1 = (const float*)d_in[9];
  const float* ba1 = (const float*)d_in[10];
  const float* Wa2 = (const float*)d_in[11];
  // d_in[12] = ba2: constant along softmax axis -> mathematically a no-op
  const float* Wo  = (const float*)d_in[13];
  const float* bo  = (const float*)d_in[14];

  if (ws_size < 313472) return;
  char* ws = (char*)d_ws;
  unsigned short* Ws2f    = (unsigned short*)(ws + 0);       // 131072 B
  unsigned short* Wof     = (unsigned short*)(ws + 131072);  // 131072 B
  unsigned short* WsWa1f  = (unsigned short*)(ws + 262144);  // 16384 B
  unsigned short* Wp2f    = (unsigned short*)(ws + 278528);  // 16384 B
  unsigned short* Wa2f    = (unsigned short*)(ws + 294912);  // 16384 B
  unsigned short* Wp2Wa1f = (unsigned short*)(ws + 311296);  // 2048 B
  float*          bh      = (float*)(ws + 313344);           // 128 B
  unsigned short* xbuf    = (unsigned short*)(ws + 313472);  // 8388608 B

  prepw<<<dim3(320), dim3(256), 0, stream>>>(Ws, Wa1, Wo, Wp2, Wa2, bp2, ba1,
                                             Ws2f, Wof, WsWa1f, Wp2f, Wa2f, Wp2Wa1f, bh);

  if (ws_size >= 313472 + 8388608) {
    attn_x<<<dim3(4096), dim3(256), 0, stream>>>(q, k, pos, msk, Wp1, bp1, bp2, bh,
                                                 Ws2f, WsWa1f, Wp2f, Wa2f, Wp2Wa1f, xbuf);
    proj<<<dim3(512), dim3(128), 0, stream>>>(xbuf, Wof, bo, (float*)d_out);
  } else {
    attn_mono<<<dim3(4096), dim3(256), 0, stream>>>(q, k, pos, msk, Wp1, bp1, bp2, bo, bh,
                                                    Ws2f, WsWa1f, Wp2f, Wa2f, Wp2Wa1f, Wof,
                                                    (float*)d_out);
  }
}